// Round 14
// baseline (1291.496 us; speedup 1.0000x reference)
//
#include <hip/hip_runtime.h>
#include <stdint.h>

#define D_    1024
#define BB    4
#define SDEC  1024
#define STXT  512
#define TDEC  4096
#define TTXT  2048
#define NH    16
#define DHD   64
#define NE    8
#define DFF   4096
#define NSLOT 8192
#define ND1   8192
#define ND2   4096
#define MOEGRID 1280

using u16 = unsigned short;
typedef __attribute__((ext_vector_type(8))) short bf16x8;
typedef __attribute__((ext_vector_type(4))) float f32x4;

__device__ __forceinline__ float bf2f(u16 h) {
    union { unsigned int u; float f; } x; x.u = ((unsigned int)h) << 16; return x.f;
}
__device__ __forceinline__ u16 f2bf(float f) {
    union { float f; unsigned int u; } x; x.f = f;
    unsigned int lsb = (x.u >> 16) & 1u;
    return (u16)((x.u + 0x7fffu + lsb) >> 16);
}

// async global->LDS, 16B per lane, linear LDS dest (wave-uniform base + lane*16)
__device__ __forceinline__ void gld16(const u16* g, u16* l) {
    __builtin_amdgcn_global_load_lds((const __attribute__((address_space(1))) void*)g,
                                     (__attribute__((address_space(3))) void*)l,
                                     16, 0, 0);
}

// ---------------------------------------------------------------------------
// Projection GEMM, BK=64: C = A * BT^T. 3-pass H/L split, G4 both-sides swizzle.
// ---------------------------------------------------------------------------
template<int EPI>
__global__ __launch_bounds__(256) void proj_k64(
    const u16* __restrict__ AH, const u16* __restrict__ AL,
    const u16* __restrict__ BH, const u16* __restrict__ BL,
    float* __restrict__ Cf, u16* __restrict__ CH, u16* __restrict__ CL,
    int M, int N, int ldc)
{
    __shared__ u16 smem[24576];
    u16* sAH = smem;
    u16* sAL = smem + 8192;
    u16* sBH = smem + 16384;
    u16* sBL = smem + 20480;

    const int tileM = blockIdx.y * 128, tileN = blockIdx.x * 64;
    const int t = threadIdx.x;
    const int srow = t >> 3;
    const int scol = ((t & 7) ^ (srow & 7)) << 3;
    const u16* pA  = AH + (long)(tileM + srow) * 1024 + scol;
    const u16* pAl = AL + (long)(tileM + srow) * 1024 + scol;
    const u16* pB  = BH + (long)(tileN + srow) * 1024 + scol;
    const u16* pBl = BL + (long)(tileN + srow) * 1024 + scol;

    const int lane = t & 63, wv = t >> 6;
    const int wr = wv << 5;
    const int fr = lane & 15, kg = lane >> 4;

    f32x4 acc[2][4];
    const f32x4 vzero = {0.f, 0.f, 0.f, 0.f};
#pragma unroll
    for (int m = 0; m < 2; ++m)
#pragma unroll
        for (int n = 0; n < 4; ++n) acc[m][n] = vzero;

    for (int rr = 0; rr < 16; ++rr) {
        const long k0 = (long)rr << 6;
#pragma unroll
        for (int c = 0; c < 4; ++c) {
            const long ro = 32L * c * 1024;
            gld16(pA  + k0 + ro, sAH + c * 2048 + t * 8);
            gld16(pAl + k0 + ro, sAL + c * 2048 + t * 8);
        }
#pragma unroll
        for (int c = 0; c < 2; ++c) {
            const long ro = 32L * c * 1024;
            gld16(pB  + k0 + ro, sBH + c * 2048 + t * 8);
            gld16(pBl + k0 + ro, sBL + c * 2048 + t * 8);
        }
        __syncthreads();

#pragma unroll
        for (int ks = 0; ks < 2; ++ks) {
            bf16x8 fa[2], fb[4], fal[2], fbl[4];
#pragma unroll
            for (int m = 0; m < 2; ++m) {
                const int r = wr + m * 16 + fr;
                const int o = r * 64 + (((kg | (ks << 2)) ^ (r & 7)) << 3);
                fa[m]  = *(const bf16x8*)&sAH[o];
                fal[m] = *(const bf16x8*)&sAL[o];
            }
#pragma unroll
            for (int n = 0; n < 4; ++n) {
                const int r = n * 16 + fr;
                const int o = r * 64 + (((kg | (ks << 2)) ^ (r & 7)) << 3);
                fb[n]  = *(const bf16x8*)&sBH[o];
                fbl[n] = *(const bf16x8*)&sBL[o];
            }
#pragma unroll
            for (int m = 0; m < 2; ++m)
#pragma unroll
                for (int n = 0; n < 4; ++n) {
                    acc[m][n] = __builtin_amdgcn_mfma_f32_16x16x32_bf16(fa[m],  fb[n],  acc[m][n], 0, 0, 0);
                    acc[m][n] = __builtin_amdgcn_mfma_f32_16x16x32_bf16(fa[m],  fbl[n], acc[m][n], 0, 0, 0);
                    acc[m][n] = __builtin_amdgcn_mfma_f32_16x16x32_bf16(fal[m], fb[n],  acc[m][n], 0, 0, 0);
                }
        }
        __syncthreads();
    }

#pragma unroll
    for (int m = 0; m < 2; ++m) {
        const int r0 = tileM + wr + m * 16 + (kg << 2);
#pragma unroll
        for (int n = 0; n < 4; ++n) {
            const int col = tileN + n * 16 + fr;
#pragma unroll
            for (int i = 0; i < 4; ++i) {
                const float v = acc[m][n][i];
                const long off = (long)(r0 + i) * ldc + col;
                if constexpr (EPI == 0) {
                    Cf[off] = v;
                } else {
                    const u16 h = f2bf(v);
                    CH[off] = h;
                    CL[off] = f2bf(v - bf2f(h));
                }
            }
        }
    }
}

// ---------------------------------------------------------------------------
// Scores GEMM, K=64 fixed: ONE staging round, ONE barrier, 96 MFMAs (3-pass).
// ---------------------------------------------------------------------------
__global__ __launch_bounds__(256) void scores_k64(
    const u16* __restrict__ AH, const u16* __restrict__ AL,
    const u16* __restrict__ BH, const u16* __restrict__ BL,
    u16* __restrict__ CH, u16* __restrict__ CL,
    int lda, int ldb, int ldc, int nb2,
    long strA1, long strA2, long strB1, long strB2, long strC1, long strC2)
{
    __shared__ u16 smem[4 * 8192];
    u16* sAH = smem;
    u16* sAL = smem + 8192;
    u16* sBH = smem + 16384;
    u16* sBL = smem + 24576;

    const int z = blockIdx.z;
    const int z1 = z / nb2, z2 = z % nb2;
    const long zA = (long)z1 * strA1 + (long)z2 * strA2;
    const long zB = (long)z1 * strB1 + (long)z2 * strB2;
    const long zC = (long)z1 * strC1 + (long)z2 * strC2;

    const int tileM = blockIdx.y * 128, tileN = blockIdx.x * 128;
    const int t = threadIdx.x;
    const int srow = t >> 3;
    const int scol = ((t & 7) ^ (srow & 7)) << 3;
    const u16* pA  = AH + zA + (long)(tileM + srow) * lda + scol;
    const u16* pAl = AL + zA + (long)(tileM + srow) * lda + scol;
    const u16* pB  = BH + zB + (long)(tileN + srow) * ldb + scol;
    const u16* pBl = BL + zB + (long)(tileN + srow) * ldb + scol;

#pragma unroll
    for (int c = 0; c < 4; ++c) {
        const long ro = 32L * c * lda;
        const long rb = 32L * c * ldb;
        gld16(pA  + ro, sAH + c * 2048 + t * 8);
        gld16(pAl + ro, sAL + c * 2048 + t * 8);
        gld16(pB  + rb, sBH + c * 2048 + t * 8);
        gld16(pBl + rb, sBL + c * 2048 + t * 8);
    }
    __syncthreads();

    const int lane = t & 63;
    const int wv = t >> 6;
    const int wr = (wv >> 1) << 6, wc = (wv & 1) << 6;
    const int fr = lane & 15, kg = lane >> 4;

    f32x4 acc[4][4];
    const f32x4 vzero = {0.f, 0.f, 0.f, 0.f};
#pragma unroll
    for (int m = 0; m < 4; ++m)
#pragma unroll
        for (int n = 0; n < 4; ++n) acc[m][n] = vzero;

#pragma unroll
    for (int ks = 0; ks < 2; ++ks) {
        bf16x8 fa[4], fb[4], fal[4], fbl[4];
#pragma unroll
        for (int m = 0; m < 4; ++m) {
            const int r = wr + m * 16 + fr;
            const int o = r * 64 + (((kg | (ks << 2)) ^ (r & 7)) << 3);
            fa[m]  = *(const bf16x8*)&sAH[o];
            fal[m] = *(const bf16x8*)&sAL[o];
        }
#pragma unroll
        for (int n = 0; n < 4; ++n) {
            const int r = wc + n * 16 + fr;
            const int o = r * 64 + (((kg | (ks << 2)) ^ (r & 7)) << 3);
            fb[n]  = *(const bf16x8*)&sBH[o];
            fbl[n] = *(const bf16x8*)&sBL[o];
        }
#pragma unroll
        for (int m = 0; m < 4; ++m)
#pragma unroll
            for (int n = 0; n < 4; ++n) {
                acc[m][n] = __builtin_amdgcn_mfma_f32_16x16x32_bf16(fa[m],  fb[n],  acc[m][n], 0, 0, 0);
                acc[m][n] = __builtin_amdgcn_mfma_f32_16x16x32_bf16(fa[m],  fbl[n], acc[m][n], 0, 0, 0);
                acc[m][n] = __builtin_amdgcn_mfma_f32_16x16x32_bf16(fal[m], fb[n],  acc[m][n], 0, 0, 0);
            }
    }

#pragma unroll
    for (int m = 0; m < 4; ++m) {
        const int r0 = tileM + wr + m * 16 + (kg << 2);
#pragma unroll
        for (int n = 0; n < 4; ++n) {
            const int col = tileN + wc + n * 16 + fr;
#pragma unroll
            for (int i = 0; i < 4; ++i) {
                const float v = acc[m][n][i];
                const long off = zC + (long)(r0 + i) * ldc + col;
                const u16 h = f2bf(v);
                CH[off] = h;
                CL[off] = f2bf(v - bf2f(h));
            }
        }
    }
}

// ---------------------------------------------------------------------------
// PV GEMM, split-K=4, BK=64. 3-pass split. grid (4, 8, NZ).
// ---------------------------------------------------------------------------
__global__ __launch_bounds__(256) void pv_k64(
    const u16* __restrict__ PHp, const u16* __restrict__ PLp,
    const u16* __restrict__ VTH, const u16* __restrict__ VTL,
    float* __restrict__ Op, int Skv, int NZ)
{
    __shared__ u16 smem[24576];
    u16* sAH = smem;
    u16* sAL = smem + 8192;
    u16* sBH = smem + 16384;
    u16* sBL = smem + 20480;

    const int kq = blockIdx.x;
    const int tileM = blockIdx.y * 128;
    const int z = blockIdx.z;
    const int kbase = kq * (Skv >> 2);
    const int nrounds = Skv >> 8;

    const int t = threadIdx.x;
    const int srow = t >> 3;
    const int scol = ((t & 7) ^ (srow & 7)) << 3;
    const u16* pA  = PHp + (long)z * 1024 * Skv + (long)(tileM + srow) * Skv + kbase + scol;
    const u16* pAl = PLp + (long)z * 1024 * Skv + (long)(tileM + srow) * Skv + kbase + scol;
    const u16* pB  = VTH + (long)z * 64 * Skv + (long)srow * Skv + kbase + scol;
    const u16* pBl = VTL + (long)z * 64 * Skv + (long)srow * Skv + kbase + scol;

    const int lane = t & 63, wv = t >> 6;
    const int wr = wv << 5;
    const int fr = lane & 15, kg = lane >> 4;

    f32x4 acc[2][4];
    const f32x4 vzero = {0.f, 0.f, 0.f, 0.f};
#pragma unroll
    for (int m = 0; m < 2; ++m)
#pragma unroll
        for (int n = 0; n < 4; ++n) acc[m][n] = vzero;

    for (int rr = 0; rr < nrounds; ++rr) {
        const long k0 = (long)rr << 6;
#pragma unroll
        for (int c = 0; c < 4; ++c) {
            const long ro = 32L * c * Skv;
            gld16(pA  + k0 + ro, sAH + c * 2048 + t * 8);
            gld16(pAl + k0 + ro, sAL + c * 2048 + t * 8);
        }
#pragma unroll
        for (int c = 0; c < 2; ++c) {
            const long ro = 32L * c * Skv;
            gld16(pB  + k0 + ro, sBH + c * 2048 + t * 8);
            gld16(pBl + k0 + ro, sBL + c * 2048 + t * 8);
        }
        __syncthreads();

#pragma unroll
        for (int ks = 0; ks < 2; ++ks) {
            bf16x8 fa[2], fb[4], fal[2], fbl[4];
#pragma unroll
            for (int m = 0; m < 2; ++m) {
                const int r = wr + m * 16 + fr;
                const int o = r * 64 + (((kg | (ks << 2)) ^ (r & 7)) << 3);
                fa[m]  = *(const bf16x8*)&sAH[o];
                fal[m] = *(const bf16x8*)&sAL[o];
            }
#pragma unroll
            for (int n = 0; n < 4; ++n) {
                const int r = n * 16 + fr;
                const int o = r * 64 + (((kg | (ks << 2)) ^ (r & 7)) << 3);
                fb[n]  = *(const bf16x8*)&sBH[o];
                fbl[n] = *(const bf16x8*)&sBL[o];
            }
#pragma unroll
            for (int m = 0; m < 2; ++m)
#pragma unroll
                for (int n = 0; n < 4; ++n) {
                    acc[m][n] = __builtin_amdgcn_mfma_f32_16x16x32_bf16(fa[m],  fb[n],  acc[m][n], 0, 0, 0);
                    acc[m][n] = __builtin_amdgcn_mfma_f32_16x16x32_bf16(fa[m],  fbl[n], acc[m][n], 0, 0, 0);
                    acc[m][n] = __builtin_amdgcn_mfma_f32_16x16x32_bf16(fal[m], fb[n],  acc[m][n], 0, 0, 0);
                }
        }
        __syncthreads();
    }

    const long base = ((long)kq * NZ + z) * 65536;
#pragma unroll
    for (int m = 0; m < 2; ++m) {
        const int r0 = tileM + wr + m * 16 + (kg << 2);
#pragma unroll
        for (int n = 0; n < 4; ++n) {
            const int col = n * 16 + fr;
#pragma unroll
            for (int i = 0; i < 4; ++i)
                Op[base + (long)(r0 + i) * 64 + col] = acc[m][n][i];
        }
    }
}

// ---------------------------------------------------------------------------
// Sum 4 PV partials, split to aoH/aoL.
// ---------------------------------------------------------------------------
__global__ __launch_bounds__(256) void pv_combine(
    const float* __restrict__ Op, u16* __restrict__ aoH, u16* __restrict__ aoL,
    int nz, int nh)
{
    const long i = ((long)blockIdx.x * 256 + threadIdx.x) * 4;
    const int zz = (int)(i >> 16);
    const int rem = (int)(i & 65535);
    const int r = rem >> 6, c = rem & 63;
    const int b = zz / nh, h = zz % nh;
    const long kqS = (long)nz * 65536;
    float4 v = *(const float4*)(Op + i);
    const float4 v1 = *(const float4*)(Op + kqS + i);
    const float4 v2 = *(const float4*)(Op + 2 * kqS + i);
    const float4 v3 = *(const float4*)(Op + 3 * kqS + i);
    v.x += v1.x + v2.x + v3.x;
    v.y += v1.y + v2.y + v3.y;
    v.z += v1.z + v2.z + v3.z;
    v.w += v1.w + v2.w + v3.w;
    const long dst = (long)b * SDEC * D_ + (long)r * D_ + h * 64 + c;
    u16 h0 = f2bf(v.x), h1 = f2bf(v.y), h2 = f2bf(v.z), h3 = f2bf(v.w);
    uint2 hh;
    hh.x = (unsigned)h0 | ((unsigned)h1 << 16);
    hh.y = (unsigned)h2 | ((unsigned)h3 << 16);
    *(uint2*)(aoH + dst) = hh;
    u16 l0 = f2bf(v.x - bf2f(h0)), l1 = f2bf(v.y - bf2f(h1));
    u16 l2 = f2bf(v.z - bf2f(h2)), l3 = f2bf(v.w - bf2f(h3));
    uint2 ll;
    ll.x = (unsigned)l0 | ((unsigned)l1 << 16);
    ll.y = (unsigned)l2 | ((unsigned)l3 << 16);
    *(uint2*)(aoL + dst) = ll;
}

// ---------------------------------------------------------------------------
// MoE persistent GEMM, BK=64 drain rounds (scores_k64 round geometry), 1-pass
// bf16, 32 KB LDS -> 5 blocks/CU. desc int4 worklist + XCD affinity unchanged.
// ---------------------------------------------------------------------------
template<int EPI>
__global__ __launch_bounds__(256) void moe_gemm2(
    const u16* __restrict__ Ag, int lda,
    const u16* __restrict__ BTbase, int ldb, long btStride,
    float* __restrict__ Cf0, float* __restrict__ Cf1, u16* __restrict__ CH, int ldc,
    const int4* __restrict__ desc, int ndesc, int Kiter)
{
    __shared__ u16 smem[16384];   // 32 KB: sA[128][64] sB[128][64]
    u16* sA = smem;
    u16* sB = smem + 8192;

    const int t = threadIdx.x;
    const int lane = t & 63, wv = t >> 6;
    const int wr = (wv >> 1) << 6, wc = (wv & 1) << 6;
    const int fr = lane & 15, kg = lane >> 4;
    const int nrounds = Kiter >> 6;

    const int srow = t >> 3;
    const int scol = ((t & 7) ^ (srow & 7)) << 3;

    for (int p = blockIdx.x; p < ndesc; p += MOEGRID) {
        const int4 d = desc[p];
        if (d.x < 0) continue;
        const int rowbase = d.x, colbase = d.y & 0xFFFF, e = d.y >> 16;
        const int kbase = d.z, s1 = d.w;
        const u16* pA = Ag + (long)(rowbase + srow) * lda + kbase + scol;
        const u16* pB = BTbase + (long)e * btStride + (long)(colbase + srow) * ldb + kbase + scol;

        f32x4 acc[4][4];
        const f32x4 vzero = {0.f, 0.f, 0.f, 0.f};
#pragma unroll
        for (int m = 0; m < 4; ++m)
#pragma unroll
            for (int n = 0; n < 4; ++n) acc[m][n] = vzero;

        for (int rr = 0; rr < nrounds; ++rr) {
            const long k0 = (long)rr << 6;
#pragma unroll
            for (int c = 0; c < 4; ++c) {
                gld16(pA + k0 + 32L * c * lda, sA + c * 2048 + t * 8);
                gld16(pB + k0 + 32L * c * ldb, sB + c * 2048 + t * 8);
            }
            __syncthreads();

#pragma unroll
            for (int ks = 0; ks < 2; ++ks) {
                bf16x8 fa[4], fb[4];
#pragma unroll
                for (int m = 0; m < 4; ++m) {
                    const int r = wr + m * 16 + fr;
                    fa[m] = *(const bf16x8*)&sA[r * 64 + (((kg | (ks << 2)) ^ (r & 7)) << 3)];
                }
#pragma unroll
                for (int n = 0; n < 4; ++n) {
                    const int r = wc + n * 16 + fr;
                    fb[n] = *(const bf16x8*)&sB[r * 64 + (((kg | (ks << 2)) ^ (r & 7)) << 3)];
                }
#pragma unroll
                for (int m = 0; m < 4; ++m)
#pragma unroll
                    for (int n = 0; n < 4; ++n)
                        acc[m][n] = __builtin_amdgcn_mfma_f32_16x16x32_bf16(fa[m], fb[n], acc[m][n], 0, 0, 0);
            }
            __syncthreads();
        }

        float* __restrict__ C = (EPI == 0) ? ((kbase == 0) ? Cf0 : Cf1) : nullptr;
#pragma unroll
        for (int m = 0; m < 4; ++m) {
            const int r0 = rowbase + wr + m * 16 + (kg << 2);
#pragma unroll
            for (int n = 0; n < 4; ++n) {
                const int col = colbase + wc + n * 16 + fr;
#pragma unroll
                for (int i = 0; i < 4; ++i) {
                    const int r = r0 + i;
                    if (r >= s1) continue;
                    const float v = acc[m][n][i];
                    const long off = (long)r * ldc + col;
                    if constexpr (EPI == 0) C[off] = v;
                    else                    CH[off] = f2bf(fmaxf(v, 0.f));
                }
            }
        }
    }
}

// ---------------------------------------------------------------------------
__global__ __launch_bounds__(256) void split2k(const float* __restrict__ in,
                                               u16* __restrict__ oh, u16* __restrict__ ol, long n)
{
    long i = ((long)blockIdx.x * 256 + threadIdx.x) * 4;
    if (i >= n) return;
    float4 v = *(const float4*)(in + i);
    u16 h0 = f2bf(v.x), h1 = f2bf(v.y), h2 = f2bf(v.z), h3 = f2bf(v.w);
    uint2 oo;
    oo.x = (unsigned)h0 | ((unsigned)h1 << 16);
    oo.y = (unsigned)h2 | ((unsigned)h3 << 16);
    *(uint2*)(oh + i) = oo;
    if (ol) {
        u16 l0 = f2bf(v.x - bf2f(h0)), l1 = f2bf(v.y - bf2f(h1));
        u16 l2 = f2bf(v.z - bf2f(h2)), l3 = f2bf(v.w - bf2f(h3));
        uint2 ll;
        ll.x = (unsigned)l0 | ((unsigned)l1 << 16);
        ll.y = (unsigned)l2 | ((unsigned)l3 << 16);
        *(uint2*)(ol + i) = ll;
    }
}

// ---------------------------------------------------------------------------
struct Ptr8 { const float* p[8]; };
__global__ __launch_bounds__(256) void transpose_split_w(
    Ptr8 in, u16* __restrict__ oh, u16* __restrict__ ol)
{
    __shared__ float tile[32][33];
    const int z = blockIdx.z;
    const float* ip = in.p[z];
    u16* ohp = oh + (long)z * D_ * D_;
    u16* olp = ol + (long)z * D_ * D_;
    const int c0 = blockIdx.x * 32, r0 = blockIdx.y * 32;
    const int tx = threadIdx.x & 31, ty = threadIdx.x >> 5;
    for (int i = ty; i < 32; i += 8)
        tile[i][tx] = ip[(long)(r0 + i) * D_ + c0 + tx];
    __syncthreads();
    for (int i = ty; i < 32; i += 8) {
        int oc = c0 + i, orr = r0 + tx;
        float v = tile[tx][i];
        u16 h = f2bf(v);
        ohp[(long)oc * D_ + orr] = h;
        olp[(long)oc * D_ + orr] = f2bf(v - bf2f(h));
    }
}

// ---------------------------------------------------------------------------
__global__ __launch_bounds__(256) void transpose_split(
    const float* __restrict__ in, u16* __restrict__ oh, u16* __restrict__ ol,
    int R, int C, int ild, long ibs1, long ibs2, int nb2, int old_, long obs)
{
    __shared__ float tile[32][33];
    const int z = blockIdx.z;
    const float* ip = in + (long)(z / nb2) * ibs1 + (long)(z % nb2) * ibs2;
    u16* ohp = oh + (long)z * obs;
    u16* olp = ol ? ol + (long)z * obs : nullptr;
    const int c0 = blockIdx.x * 32, r0 = blockIdx.y * 32;
    const int tx = threadIdx.x & 31, ty = threadIdx.x >> 5;
    for (int i = ty; i < 32; i += 8) {
        int r = r0 + i, c = c0 + tx;
        tile[i][tx] = (r < R && c < C) ? ip[(long)r * ild + c] : 0.f;
    }
    __syncthreads();
    for (int i = ty; i < 32; i += 8) {
        int oc = c0 + i, orr = r0 + tx;
        if (oc < C && orr < R) {
            float v = tile[tx][i];
            u16 h = f2bf(v);
            ohp[(long)oc * old_ + orr] = h;
            if (olp) olp[(long)oc * old_ + orr] = f2bf(v - bf2f(h));
        }
    }
}

// ---------------------------------------------------------------------------
__global__ __launch_bounds__(256) void transpose_split_hl(
    const u16* __restrict__ inH, const u16* __restrict__ inL,
    u16* __restrict__ oh, u16* __restrict__ ol,
    int R, int C, int ild, long ibs1, long ibs2, int nb2, int old_, long obs)
{
    __shared__ float tile[32][33];
    const int z = blockIdx.z;
    const long base = (long)(z / nb2) * ibs1 + (long)(z % nb2) * ibs2;
    u16* ohp = oh + (long)z * obs;
    u16* olp = ol + (long)z * obs;
    const int c0 = blockIdx.x * 32, r0 = blockIdx.y * 32;
    const int tx = threadIdx.x & 31, ty = threadIdx.x >> 5;
    for (int i = ty; i < 32; i += 8) {
        int r = r0 + i, c = c0 + tx;
        float v = 0.f;
        if (r < R && c < C) {
            const long o = base + (long)r * ild + c;
            v = bf2f(inH[o]) + bf2f(inL[o]);
        }
        tile[i][tx] = v;
    }
    __syncthreads();
    for (int i = ty; i < 32; i += 8) {
        int oc = c0 + i, orr = r0 + tx;
        if (oc < C && orr < R) {
            float v = tile[tx][i];
            u16 h = f2bf(v);
            ohp[(long)oc * old_ + orr] = h;
            olp[(long)oc * old_ + orr] = f2bf(v - bf2f(h));
        }
    }
}

// ---------------------------------------------------------------------------
// In-place softmax over bf16 hi/lo scores.
// ---------------------------------------------------------------------------
__global__ __launch_bounds__(256) void softmax_hl(
    u16* __restrict__ ph, u16* __restrict__ pl, int cols, float scale)
{
    u16* php = ph + (long)blockIdx.x * cols;
    u16* plp = pl + (long)blockIdx.x * cols;
    const int t = threadIdx.x;
    float v[4];
    int vpt;
    if (cols == 1024) {
        vpt = 4;
        uint2 hh = ((const uint2*)php)[t];
        uint2 ll = ((const uint2*)plp)[t];
        v[0] = (bf2f((u16)(hh.x & 0xffff)) + bf2f((u16)(ll.x & 0xffff))) * scale;
        v[1] = (bf2f((u16)(hh.x >> 16))    + bf2f((u16)(ll.x >> 16)))    * scale;
        v[2] = (bf2f((u16)(hh.y & 0xffff)) + bf2f((u16)(ll.y & 0xffff))) * scale;
        v[3] = (bf2f((u16)(hh.y >> 16))    + bf2f((u16)(ll.y >> 16)))    * scale;
    } else {
        vpt = 2;
        unsigned hh = ((const unsigned*)php)[t];
        unsigned ll = ((const unsigned*)plp)[t];
        v[0] = (bf2f((u16)(hh & 0xffff)) + bf2f((u16)(ll & 0xffff))) * scale;
        v[1] = (bf2f((u16)(hh >> 16))    + bf2f((u16)(ll >> 16)))    * scale;
        v[2] = -3.4e38f; v[3] = -3.4e38f;
    }
    float mx = fmaxf(fmaxf(v[0], v[1]), fmaxf(v[2], v[3]));
#pragma unroll
    for (int o = 32; o; o >>= 1) mx = fmaxf(mx, __shfl_xor(mx, o));
    __shared__ float sm[4];
    const int wv = t >> 6, ln = t & 63;
    if (ln == 0) sm[wv] = mx;
    __syncthreads();
    mx = fmaxf(fmaxf(sm[0], sm[1]), fmaxf(sm[2], sm[3]));
    float sum = 0.f;
    for (int i = 0; i < vpt; ++i) { v[i] = expf(v[i] - mx); sum += v[i]; }
#pragma unroll
    for (int o = 32; o; o >>= 1) sum += __shfl_xor(sum, o);
    __shared__ float ss[4];
    if (ln == 0) ss[wv] = sum;
    __syncthreads();
    sum = ss[0] + ss[1] + ss[2] + ss[3];
    const float inv = 1.f / sum;
    if (cols == 1024) {
        float q0 = v[0] * inv, q1 = v[1] * inv, q2 = v[2] * inv, q3 = v[3] * inv;
        u16 h0 = f2bf(q0), h1 = f2bf(q1), h2 = f2bf(q2), h3 = f2bf(q3);
        uint2 hh; hh.x = (unsigned)h0 | ((unsigned)h1 << 16); hh.y = (unsigned)h2 | ((unsigned)h3 << 16);
        ((uint2*)php)[t] = hh;
        u16 l0 = f2bf(q0 - bf2f(h0)), l1 = f2bf(q1 - bf2f(h1));
        u16 l2 = f2bf(q2 - bf2f(h2)), l3 = f2bf(q3 - bf2f(h3));
        uint2 llo; llo.x = (unsigned)l0 | ((unsigned)l1 << 16); llo.y = (unsigned)l2 | ((unsigned)l3 << 16);
        ((uint2*)plp)[t] = llo;
    } else {
        float q0 = v[0] * inv, q1 = v[1] * inv;
        u16 h0 = f2bf(q0), h1 = f2bf(q1);
        ((unsigned*)php)[t] = (unsigned)h0 | ((unsigned)h1 << 16);
        u16 l0 = f2bf(q0 - bf2f(h0)), l1 = f2bf(q1 - bf2f(h1));
        ((unsigned*)plp)[t] = (unsigned)l0 | ((unsigned)l1 << 16);
    }
}

// ---------------------------------------------------------------------------
__global__ __launch_bounds__(256) void add_rmsnorm(
    const float* __restrict__ a, const float* __restrict__ b, const float* __restrict__ g,
    float* __restrict__ xo, u16* __restrict__ xh, u16* __restrict__ xl)
{
    const long row = blockIdx.x;
    const int t = threadIdx.x;
    const float* pa = a + row * D_;
    const float* pb = b + row * D_;
    float v[4]; double ssq = 0.0;
#pragma unroll
    for (int i = 0; i < 4; ++i) {
        int c = t + (i << 8);
        v[i] = pa[c] + pb[c];
        ssq += (double)v[i] * v[i];
    }
#pragma unroll
    for (int o = 32; o; o >>= 1) ssq += __shfl_xor(ssq, o);
    __shared__ double sd[4];
    if ((t & 63) == 0) sd[t >> 6] = ssq;
    __syncthreads();
    ssq = sd[0] + sd[1] + sd[2] + sd[3];
    const float rs = (float)(1.0 / sqrt(ssq * (1.0 / 1024.0) + 1e-6));
#pragma unroll
    for (int i = 0; i < 4; ++i) {
        int c = t + (i << 8);
        float o = v[i] * rs * g[c];
        xo[row * D_ + c] = o;
        if (xh) {
            u16 h = f2bf(o);
            xh[row * D_ + c] = h;
            if (xl) xl[row * D_ + c] = f2bf(o - bf2f(h));
        }
    }
}

// ---------------------------------------------------------------------------
__global__ __launch_bounds__(256) void router_topk(
    const float* __restrict__ x2, const float* __restrict__ Wg,
    float* __restrict__ outw, float* __restrict__ outi,
    int* __restrict__ idx, float* __restrict__ tokw, int* __restrict__ counts, int T)
{
    const int wid = (int)((blockIdx.x * 256 + threadIdx.x) >> 6);
    const int lane = threadIdx.x & 63;
    if (wid >= T) return;
    float acc[NE];
#pragma unroll
    for (int e = 0; e < NE; ++e) acc[e] = 0.f;
    const float* xr = x2 + (long)wid * D_;
    for (int i = 0; i < 16; ++i) {
        float xv = xr[i * 64 + lane];
        const float* wr = Wg + (long)(i * 64 + lane) * NE;
#pragma unroll
        for (int e = 0; e < NE; ++e) acc[e] += xv * wr[e];
    }
#pragma unroll
    for (int e = 0; e < NE; ++e)
#pragma unroll
        for (int o = 32; o; o >>= 1) acc[e] += __shfl_xor(acc[e], o);
    if (lane == 0) {
        float m = acc[0];
#pragma unroll
        for (int e = 1; e < NE; ++e) m = fmaxf(m, acc[e]);
        float p[NE], s = 0.f;
#pragma unroll
        for (int e = 0; e < NE; ++e) { p[e] = expf(acc[e] - m); s += p[e]; }
        const float invs = 1.f / s;
#pragma unroll
        for (int e = 0; e < NE; ++e) p[e] *= invs;
        int e0 = 0;
#pragma unroll
        for (int e = 1; e < NE; ++e) if (p[e] > p[e0]) e0 = e;
        int e1 = (e0 == 0) ? 1 : 0;
#pragma unroll
        for (int e = 0; e < NE; ++e) if (e != e0 && e != e1 && p[e] > p[e1]) e1 = e;
        float w0 = p[e0], w1 = p[e1];
        const float sw = 1.f / (w0 + w1);
        w0 *= sw; w1 *= sw;
        outw[2 * wid] = w0;      outw[2 * wid + 1] = w1;
        outi[2 * wid] = (float)e0; outi[2 * wid + 1] = (float)e1;
        idx[2 * wid] = e0;       idx[2 * wid + 1] = e1;
        tokw[2 * wid] = w0;      tokw[2 * wid + 1] = w1;
        atomicAdd(&counts[e0], 1);
        atomicAdd(&counts[e1], 1);
    }
}

// ---------------------------------------------------------------------------
__global__ void scan_desc(const int* __restrict__ counts, int* __restrict__ cursor,
                          int4* __restrict__ d1, int4* __restrict__ d2)
{
    __shared__ int sseg[NE + 1];
    if (threadIdx.x == 0) {
        int a = 0;
        for (int e = 0; e < NE; ++e) { sseg[e] = a; cursor[e] = a; a += counts[e]; }
        sseg[NE] = a;
    }
    __syncthreads();
    const int e = threadIdx.x;
    if (e < NE) {
        const int s0 = sseg[e], s1 = sseg[e + 1];
        const int nyt = (s1 - s0 + 127) >> 7;
        for (int xt = 0; xt < 32; ++xt)
            for (int yt = 0; yt < nyt; ++yt)
                d1[e + 8 * (xt * nyt + yt)] =
                    make_int4(s0 + yt * 128, (xt * 128) | (e << 16), 0, s1);
        for (int kh = 0; kh < 2; ++kh)
            for (int xt = 0; xt < 8; ++xt)
                for (int yt = 0; yt < nyt; ++yt)
                    d2[e + 8 * ((kh * 8 + xt) * nyt + yt)] =
                        make_int4(s0 + yt * 128, (xt * 128) | (e << 16), kh * 2048, s1);
    }
}

__global__ __launch_bounds__(256) void scatter_slots(
    const int* __restrict__ idx, int* __restrict__ cursor,
    int* __restrict__ row_token, int* __restrict__ slot_of, int T)
{
    const int t = blockIdx.x * 256 + threadIdx.x;
    if (t >= T) return;
#pragma unroll
    for (int k = 0; k < 2; ++k) {
        const int e = idx[2 * t + k];
        const int pos = atomicAdd(&cursor[e], 1);
        row_token[pos] = t;
        slot_of[2 * t + k] = pos;
    }
}

__global__ __launch_bounds__(256) void gather_bf16(
    const float* __restrict__ x2, const int* __restrict__ row_token, u16* __restrict__ Xg)
{
    const int r = blockIdx.x;
    const int t = threadIdx.x;
    const float* src = x2 + (long)row_token[r] * D_ + t * 4;
    float4 v = *(const float4*)src;
    uint2 oo;
    oo.x = (unsigned)f2bf(v.x) | ((unsigned)f2bf(v.y) << 16);
    oo.y = (unsigned)f2bf(v.z) | ((unsigned)f2bf(v.w) << 16);
    *(uint2*)(Xg + (long)r * D_ + t * 4) = oo;
}

// ---------------------------------------------------------------------------
__global__ __launch_bounds__(256) void combine_rmsnorm(
    const float* __restrict__ Y0, const float* __restrict__ Y1,
    const int* __restrict__ slot_of, const float* __restrict__ tokw,
    const float* __restrict__ x2, const float* __restrict__ g, float* __restrict__ out)
{
    const long tr = blockIdx.x;
    const int t = threadIdx.x;
    const int s0 = slot_of[2 * tr], s1 = slot_of[2 * tr + 1];
    const float w0 = tokw[2 * tr], w1 = tokw[2 * tr + 1];
    const float* ya0 = Y0 + (long)s0 * D_;
    const float* yb0 = Y1 + (long)s0 * D_;
    const float* ya1 = Y0 + (long)s1 * D_;
    const float* yb1 = Y1 + (long)s1 * D_;
    const float* xr = x2 + tr * D_;
    float v[4]; double ssq = 0.0;
#pragma unroll
    for (int i = 0; i < 4; ++i) {
        int c = t + (i << 8);
        v[i] = w0 * (ya0[c] + yb0[c]) + w1 * (ya1[c] + yb1[c]) + xr[c];
        ssq += (double)v[i] * v[i];
    }
#pragma unroll
    for (int o = 32; o; o >>= 1) ssq += __shfl_xor(ssq, o);
    __shared__ double sd[4];
    if ((t & 63) == 0) sd[t >> 6] = ssq;
    __syncthreads();
    ssq = sd[0] + sd[1] + sd[2] + sd[3];
    const float rs = (float)(1.0 / sqrt(ssq * (1.0 / 1024.0) + 1e-6));
#pragma unroll
    for (int i = 0; i < 4; ++i) {
        int c = t + (i << 8);
        out[tr * D_ + c] = v[i] * rs * g[c];
    }
}

__global__ void sentinel(float* o) { o[0] = 12345.0f; }

// ---------------------------------------------------------------------------
extern "C" void kernel_launch(void* const* d_in, const int* in_sizes, int n_in,
                              void* d_out, int out_size, void* d_ws, size_t ws_size,
                              hipStream_t stream)
{
    const float* dec = (const float*)d_in[0];
    const float* te  = (const float*)d_in[1];
    const float* g  = (const float*)d_in[10];
    const float* Wg = (const float*)d_in[11];
    const float* W1 = (const float*)d_in[12];
    const float* W2 = (const float*)d_in[13];
    float* outw = (float*)d_out;
    float* outi = outw + 2 * TDEC;
    float* outx = outw + 4 * TDEC;

    char* ws = (char*)d_ws;
    size_t off = 0;
    auto A = [&](size_t bytes) -> char* {
        char* p = ws + off;
        off += (bytes + 255) & ~(size_t)255;
        return p;
    };

    // ---- persistent region ----
    u16* decH = (u16*)A((size_t)TDEC * D_ * 2);
    u16* decL = (u16*)A((size_t)TDEC * D_ * 2);
    u16* teH  = (u16*)A((size_t)TTXT * D_ * 2);
    u16* teL  = (u16*)A((size_t)TTXT * D_ * 2);
    u16* wtHall = (u16*)A((size_t)8 * D_ * D_ * 2);
    u16* wtLall = (u16*)A((size_t)8 * D_ * D_ * 2);
    float* x1f = (float*)A((size_t)TDEC * D_ * 4);
    float* x2f = (float*)A((size_t)TDEC * D_ * 4);
    float* tokw = (float*)A(NSLOT * 4);
    int* idx    = (int*)A(NSLOT * 4);
    int* counts = (int*)A(256);
    int* cursor = (int*)A(256);
    int* row_token = (int*)A(NSLOT * 4);
    int* slot_of   = (int*)A(NSLOT * 4);
    int4* desc1 = (int4*)A((size_t)ND1 * 16);
    int4* desc2 = (int4*)A((size_t)ND2 * 16);
    const size_t Rbase = off;

    // ---- shared region: MoE view ----
    u16* W1T  = (u16*)A((size_t)NE * DFF * D_ * 2);
    u16* W2T  = (u16*)A((size_t)NE * D_ * DFF * 2);
    u16* Xg   = (u16*)A((size_t)(NSLOT + 256) * D_ * 2);
    u16* Hb   = (u16*)A((size_t)(NSLOT + 256) * DFF * 2);
    float* Yseg = (float*)A((size_t)NSLOT * D_ * 4);
    float* Ypart1 = (float*)W1T;
    const size_t moeEnd = off;

    // ---- shared region: attention view (batched preferred, fallback smaller) ----
    auto allocAttn = [&](bool batched, u16*& PH, u16*& PL, u16*& qkvH, u16*& qkvL,
                         u16*& q2H, u16*& q2L, u16*& kv2H, u16*& kv2L,
                         u16*& vTH, u16*& vTL, u16*& aoH, u16*& aoL,
                         u16*& x1H, u16*& x1L, float*& of, float*& Opart) {
        off = Rbase;
        const size_t pcell = batched ? (size_t)BB * NH * SDEC * SDEC * 2
                                     : (size_t)NH * SDEC * SDEC * 2;
        PH = (u16*)A(pcell);
        PL = (u16*)A(pcell);
        qkvH = (u16*)A((size_t)TDEC * 3 * D_ * 2);
        qkvL = (u16*)A((size_t)TDEC * 3 * D_ * 2);
        q2H  = (u16*)A((size_t)TDEC * D_ * 2);
        q2L  = (u16*)A((size_t)TDEC * D_ * 2);
        kv2H = (u16*)A((size_t)TTXT * 2 * D_ * 2);
        kv2L = (u16*)A((size_t)TTXT * 2 * D_ * 2);
        vTH = (u16*)A((size_t)TDEC * D_ * 2);
        vTL = (u16*)A((size_t)TDEC * D_ * 2);
        aoH = (u16*)A((size_t)TDEC * D_ * 2);
        aoL = (u16*)A((size_t)TDEC * D_ * 2);
        x1H = (u16*)A((size_t)TDEC * D_ * 2);
        x1L = (u16*)A((size_t)TDEC * D_ * 2);
        of  = (float*)A((size_t)TDEC * D_ * 4);
        Opart = (float*)A((size_t)4 * (batched ? BB * NH : NH) * SDEC * DHD * 4);
        return off;
    };

    u16 *PH, *PL, *qkvH, *qkvL, *q2H, *q2L, *kv2H, *kv2L, *vTH, *vTL, *aoH, *aoL, *x1H, *x1L;
    float *of, *Opart;
    size_t attnEnd = allocAttn(true, PH, PL, qkvH, qkvL, q2H, q2L, kv2H, kv2L,
                               vTH, vTL, aoH, aoL, x1H, x1L, of, Opart);
    bool batched = ws_size >= (attnEnd > moeEnd ? attnEnd : moeEnd);
    if (!batched) {
        attnEnd = allocAttn(false, PH, PL, qkvH, qkvL, q2H, q2L, kv2H, kv2L,
                            vTH, vTL, aoH, aoL, x1H, x1L, of, Opart);
        if (ws_size < (attnEnd > moeEnd ? attnEnd : moeEnd)) {
            sentinel<<<1, 1, 0, stream>>>(outw);
            return;
        }
    }

    const dim3 blk(256);

    // ---- phase 0: input splits + batched attention weight transposes ----
    split2k<<<dim3((TDEC * D_) / 1024), blk, 0, stream>>>(dec, decH, decL, (long)TDEC * D_);
    split2k<<<dim3((TTXT * D_) / 1024), blk, 0, stream>>>(te, teH, teL, (long)TTXT * D_);
    Ptr8 wp;
    for (int i = 0; i < 8; ++i) wp.p[i] = (const float*)d_in[2 + i];
    transpose_split_w<<<dim3(32, 32, 8), blk, 0, stream>>>(wp, wtHall, wtLall);

    // ---- phase 1: self-attention ----
    proj_k64<1><<<dim3(48, 32), blk, 0, stream>>>(decH, decL, wtHall, wtLall,
        nullptr, qkvH, qkvL, TDEC, 3 * D_, 3 * D_);
    transpose_split_hl<<<dim3(2, 32, BB * NH), blk, 0, stream>>>(qkvH + 2 * D_, qkvL + 2 * D_,
        vTH, vTL, SDEC, DHD, 3 * D_, (long)SDEC * 3 * D_, DHD, NH, SDEC, (long)DHD * SDEC);

    if (batched) {
        scores_k64<<<dim3(8, 8, BB * NH), blk, 0, stream>>>(
            qkvH, qkvL, qkvH + D_, qkvL + D_, PH, PL,
            3 * D_, 3 * D_, SDEC, NH,
            (long)SDEC * 3 * D_, DHD, (long)SDEC * 3 * D_, DHD,
            (long)NH * SDEC * SDEC, (long)SDEC * SDEC);
        softmax_hl<<<dim3(BB * NH * SDEC), blk, 0, stream>>>(PH, PL, SDEC, 0.125f);
        pv_k64<<<dim3(4, 8, BB * NH), blk, 0, stream>>>(PH, PL, vTH, vTL, Opart, SDEC, BB * NH);
        pv_combine<<<dim3(BB * NH * 64), blk, 0, stream>>>(Opart, aoH, aoL, BB * NH, NH);
    } else {
        for (int b = 0; b < BB; ++b) {
            const long qo3 = (long)b * SDEC * 3 * D_;
            const long qo  = (long)b * SDEC * D_;
            scores_k64<<<dim3(8, 8, NH), blk, 0, stream>>>(
                qkvH + qo3, qkvL + qo3, qkvH + qo3 + D_, qkvL + qo3 + D_,
                PH, PL, 3 * D_, 3 * D_, SDEC, NH,
                0, DHD, 0, DHD, 0, (long)SDEC * SDEC);
            softmax_hl<<<dim3(NH * SDEC), blk, 0, stream>>>(PH, PL, SDEC, 0.125f);
            pv_k64<<<dim3(4, 8, NH), blk, 0, stream>>>(PH, PL,
                vTH + (long)b * NH * DHD * SDEC, vTL + (long)b * NH * DHD * SDEC,
                Opart, SDEC, NH);
            pv_combine<<<dim3(NH * 64), blk, 0, stream>>>(Opart, aoH + qo, aoL + qo, NH, NH);
        }
    }
    proj_k64<0><<<dim3(16, 32), blk, 0, stream>>>(aoH, aoL,
        wtHall + (size_t)3 * D_ * D_, wtLall + (size_t)3 * D_ * D_,
        of, nullptr, nullptr, TDEC, D_, D_);
    add_rmsnorm<<<dim3(TDEC), blk, 0, stream>>>(of, dec, g, x1f, x1H, x1L);

    // ---- phase 2: cross-attention ----
    proj_k64<1><<<dim3(16, 32), blk, 0, stream>>>(x1H, x1L,
        wtHall + (size_t)4 * D_ * D_, wtLall + (size_t)4 * D_ * D_,
        nullptr, q2H, q2L, TDEC, D_, D_);
    proj_k64<1><<<dim3(32, 16), blk, 0, stream>>>(teH, teL,
        wtHall + (size_t)5 * D_ * D_, wtLall + (size_t)5 * D_ * D_,
        nullptr, kv2H, kv2L, TTXT, 2 * D_, 2 * D_);
    transpose_split_hl<<<dim3(2, 16, BB * NH), blk, 0, stream>>>(kv2H + D_, kv2L + D_,
        vTH, vTL, STXT, DHD, 2 * D_, (long)STXT * 2 * D_, DHD, NH, STXT, (long)DHD * STXT);

    if (batched) {
        scores_k64<<<dim3(4, 8, BB * NH), blk, 0, stream>>>(
            q2H, q2L, kv2H, kv2L, PH, PL,
            D_, 2 * D_, STXT, NH,
            (long)SDEC * D_, DHD, (long)STXT * 2 * D_, DHD,
            (long)NH * SDEC * STXT, (long)SDEC * STXT);
        softmax_hl<<<dim3(BB * NH * SDEC), blk, 0, stream>>>(PH, PL, STXT, 0.125f);
        pv_k64<<<dim3(4, 8, BB * NH), blk, 0, stream>>>(PH, PL, vTH, vTL, Opart, STXT, BB * NH);
        pv_combine<<<dim3(BB * NH * 64), blk, 0, stream>>>(Opart, aoH, aoL, BB * NH, NH);
    } else {
        for (int b = 0; b < BB; ++b) {
            const long qo  = (long)b * SDEC * D_;
            const long ko2 = (long)b * STXT * 2 * D_;
            scores_k64<<<dim3(4, 8, NH), blk, 0, stream>>>(
                q2H + qo, q2L + qo, kv2H + ko2, kv2L + ko2,
                PH, PL, D_, 2 * D_, STXT, NH,
                0, DHD, 0, DHD, 0, (long)SDEC * STXT);
            softmax_hl<<<dim3(NH * SDEC), blk, 0, stream>>>(PH, PL, STXT, 0.125f);
            pv_k64<<<dim3(4, 8, NH), blk, 0, stream>>>(PH, PL,
                vTH + (long)b * NH * DHD * STXT, vTL + (long)b * NH * DHD * STXT,
                Opart, STXT, NH);
            pv_combine<<<dim3(NH * 64), blk, 0, stream>>>(Opart, aoH + qo, aoL + qo, NH, NH);
        }
    }
    proj_k64<0><<<dim3(16, 32), blk, 0, stream>>>(aoH, aoL,
        wtHall + (size_t)7 * D_ * D_, wtLall + (size_t)7 * D_ * D_,
        of, nullptr, nullptr, TDEC, D_, D_);
    add_rmsnorm<<<dim3(TDEC), blk, 0, stream>>>(of, x1f, g, x2f, nullptr, nullptr);

    // ---- phase 3: router + expert bucketing + work lists ----
    hipMemsetAsync(counts, 0, 32, stream);
    hipMemsetAsync(desc1, 0xFF, (size_t)ND1 * 16, stream);
    hipMemsetAsync(desc2, 0xFF, (size_t)ND2 * 16, stream);
    router_topk<<<dim3(TDEC / 4), blk, 0, stream>>>(x2f, Wg, outw, outi, idx, tokw, counts, TDEC);
    scan_desc<<<1, 64, 0, stream>>>(counts, cursor, desc1, desc2);
    scatter_slots<<<dim3(TDEC / 256), blk, 0, stream>>>(idx, cursor, row_token, slot_of, TDEC);
    gather_bf16<<<dim3(NSLOT), blk, 0, stream>>>(x2f, row_token, Xg);

    // ---- phase 4: MoE FFN (persistent 128x128, BK=64 drain rounds) ----
    transpose_split<<<dim3(DFF / 32, D_ / 32, NE), blk, 0, stream>>>(W1, W1T, nullptr,
        D_, DFF, DFF, (long)D_ * DFF, 0, 1, D_, (long)DFF * D_);
    transpose_split<<<dim3(D_ / 32, DFF / 32, NE), blk, 0, stream>>>(W2, W2T, nullptr,
        DFF, D_, D_, (long)D_ * DFF, 0, 1, DFF, (long)D_ * DFF);
    moe_gemm2<2><<<dim3(MOEGRID), blk, 0, stream>>>(Xg, D_, W1T, D_, (long)DFF * D_,
        nullptr, nullptr, Hb, DFF, desc1, ND1, 1024);
    moe_gemm2<0><<<dim3(MOEGRID), blk, 0, stream>>>(Hb, DFF, W2T, DFF, (long)D_ * DFF,
        Yseg, Ypart1, nullptr, D_, desc2, ND2, 2048);
    combine_rmsnorm<<<dim3(TDEC), blk, 0, stream>>>(Yseg, Ypart1, slot_of, tokw, x2f, g, outx);

    (void)in_sizes; (void)n_in; (void)out_size;
}

// Round 15
// 1243.160 us; speedup vs baseline: 1.0389x; 1.0389x over previous
//
#include <hip/hip_runtime.h>
#include <stdint.h>

#define D_    1024
#define BB    4
#define SDEC  1024
#define STXT  512
#define TDEC  4096
#define TTXT  2048
#define NH    16
#define DHD   64
#define NE    8
#define DFF   4096
#define NSLOT 8192
#define ND1   8192
#define ND2   4096
#define MOEGRID 512

using u16 = unsigned short;
typedef __attribute__((ext_vector_type(8))) short bf16x8;
typedef __attribute__((ext_vector_type(4))) float f32x4;

__device__ __forceinline__ float bf2f(u16 h) {
    union { unsigned int u; float f; } x; x.u = ((unsigned int)h) << 16; return x.f;
}
__device__ __forceinline__ u16 f2bf(float f) {
    union { float f; unsigned int u; } x; x.f = f;
    unsigned int lsb = (x.u >> 16) & 1u;
    return (u16)((x.u + 0x7fffu + lsb) >> 16);
}

// async global->LDS, 16B per lane, linear LDS dest (wave-uniform base + lane*16)
__device__ __forceinline__ void gld16(const u16* g, u16* l) {
    __builtin_amdgcn_global_load_lds((const __attribute__((address_space(1))) void*)g,
                                     (__attribute__((address_space(3))) void*)l,
                                     16, 0, 0);
}

// ---------------------------------------------------------------------------
// Projection GEMM, BK=64: C = A * BT^T. 3-pass H/L split, G4 both-sides swizzle.
// ---------------------------------------------------------------------------
template<int EPI>
__global__ __launch_bounds__(256) void proj_k64(
    const u16* __restrict__ AH, const u16* __restrict__ AL,
    const u16* __restrict__ BH, const u16* __restrict__ BL,
    float* __restrict__ Cf, u16* __restrict__ CH, u16* __restrict__ CL,
    int M, int N, int ldc)
{
    __shared__ u16 smem[24576];
    u16* sAH = smem;
    u16* sAL = smem + 8192;
    u16* sBH = smem + 16384;
    u16* sBL = smem + 20480;

    const int tileM = blockIdx.y * 128, tileN = blockIdx.x * 64;
    const int t = threadIdx.x;
    const int srow = t >> 3;
    const int scol = ((t & 7) ^ (srow & 7)) << 3;
    const u16* pA  = AH + (long)(tileM + srow) * 1024 + scol;
    const u16* pAl = AL + (long)(tileM + srow) * 1024 + scol;
    const u16* pB  = BH + (long)(tileN + srow) * 1024 + scol;
    const u16* pBl = BL + (long)(tileN + srow) * 1024 + scol;

    const int lane = t & 63, wv = t >> 6;
    const int wr = wv << 5;
    const int fr = lane & 15, kg = lane >> 4;

    f32x4 acc[2][4];
    const f32x4 vzero = {0.f, 0.f, 0.f, 0.f};
#pragma unroll
    for (int m = 0; m < 2; ++m)
#pragma unroll
        for (int n = 0; n < 4; ++n) acc[m][n] = vzero;

    for (int rr = 0; rr < 16; ++rr) {
        const long k0 = (long)rr << 6;
#pragma unroll
        for (int c = 0; c < 4; ++c) {
            const long ro = 32L * c * 1024;
            gld16(pA  + k0 + ro, sAH + c * 2048 + t * 8);
            gld16(pAl + k0 + ro, sAL + c * 2048 + t * 8);
        }
#pragma unroll
        for (int c = 0; c < 2; ++c) {
            const long ro = 32L * c * 1024;
            gld16(pB  + k0 + ro, sBH + c * 2048 + t * 8);
            gld16(pBl + k0 + ro, sBL + c * 2048 + t * 8);
        }
        __syncthreads();

#pragma unroll
        for (int ks = 0; ks < 2; ++ks) {
            bf16x8 fa[2], fb[4], fal[2], fbl[4];
#pragma unroll
            for (int m = 0; m < 2; ++m) {
                const int r = wr + m * 16 + fr;
                const int o = r * 64 + (((kg | (ks << 2)) ^ (r & 7)) << 3);
                fa[m]  = *(const bf16x8*)&sAH[o];
                fal[m] = *(const bf16x8*)&sAL[o];
            }
#pragma unroll
            for (int n = 0; n < 4; ++n) {
                const int r = n * 16 + fr;
                const int o = r * 64 + (((kg | (ks << 2)) ^ (r & 7)) << 3);
                fb[n]  = *(const bf16x8*)&sBH[o];
                fbl[n] = *(const bf16x8*)&sBL[o];
            }
#pragma unroll
            for (int m = 0; m < 2; ++m)
#pragma unroll
                for (int n = 0; n < 4; ++n) {
                    acc[m][n] = __builtin_amdgcn_mfma_f32_16x16x32_bf16(fa[m],  fb[n],  acc[m][n], 0, 0, 0);
                    acc[m][n] = __builtin_amdgcn_mfma_f32_16x16x32_bf16(fa[m],  fbl[n], acc[m][n], 0, 0, 0);
                    acc[m][n] = __builtin_amdgcn_mfma_f32_16x16x32_bf16(fal[m], fb[n],  acc[m][n], 0, 0, 0);
                }
        }
        __syncthreads();
    }

#pragma unroll
    for (int m = 0; m < 2; ++m) {
        const int r0 = tileM + wr + m * 16 + (kg << 2);
#pragma unroll
        for (int n = 0; n < 4; ++n) {
            const int col = tileN + n * 16 + fr;
#pragma unroll
            for (int i = 0; i < 4; ++i) {
                const float v = acc[m][n][i];
                const long off = (long)(r0 + i) * ldc + col;
                if constexpr (EPI == 0) {
                    Cf[off] = v;
                } else {
                    const u16 h = f2bf(v);
                    CH[off] = h;
                    CL[off] = f2bf(v - bf2f(h));
                }
            }
        }
    }
}

// ---------------------------------------------------------------------------
// Scores GEMM, K=64 fixed: ONE staging round, ONE barrier, 96 MFMAs (3-pass).
// ---------------------------------------------------------------------------
__global__ __launch_bounds__(256) void scores_k64(
    const u16* __restrict__ AH, const u16* __restrict__ AL,
    const u16* __restrict__ BH, const u16* __restrict__ BL,
    u16* __restrict__ CH, u16* __restrict__ CL,
    int lda, int ldb, int ldc, int nb2,
    long strA1, long strA2, long strB1, long strB2, long strC1, long strC2)
{
    __shared__ u16 smem[4 * 8192];
    u16* sAH = smem;
    u16* sAL = smem + 8192;
    u16* sBH = smem + 16384;
    u16* sBL = smem + 24576;

    const int z = blockIdx.z;
    const int z1 = z / nb2, z2 = z % nb2;
    const long zA = (long)z1 * strA1 + (long)z2 * strA2;
    const long zB = (long)z1 * strB1 + (long)z2 * strB2;
    const long zC = (long)z1 * strC1 + (long)z2 * strC2;

    const int tileM = blockIdx.y * 128, tileN = blockIdx.x * 128;
    const int t = threadIdx.x;
    const int srow = t >> 3;
    const int scol = ((t & 7) ^ (srow & 7)) << 3;
    const u16* pA  = AH + zA + (long)(tileM + srow) * lda + scol;
    const u16* pAl = AL + zA + (long)(tileM + srow) * lda + scol;
    const u16* pB  = BH + zB + (long)(tileN + srow) * ldb + scol;
    const u16* pBl = BL + zB + (long)(tileN + srow) * ldb + scol;

#pragma unroll
    for (int c = 0; c < 4; ++c) {
        const long ro = 32L * c * lda;
        const long rb = 32L * c * ldb;
        gld16(pA  + ro, sAH + c * 2048 + t * 8);
        gld16(pAl + ro, sAL + c * 2048 + t * 8);
        gld16(pB  + rb, sBH + c * 2048 + t * 8);
        gld16(pBl + rb, sBL + c * 2048 + t * 8);
    }
    __syncthreads();

    const int lane = t & 63;
    const int wv = t >> 6;
    const int wr = (wv >> 1) << 6, wc = (wv & 1) << 6;
    const int fr = lane & 15, kg = lane >> 4;

    f32x4 acc[4][4];
    const f32x4 vzero = {0.f, 0.f, 0.f, 0.f};
#pragma unroll
    for (int m = 0; m < 4; ++m)
#pragma unroll
        for (int n = 0; n < 4; ++n) acc[m][n] = vzero;

#pragma unroll
    for (int ks = 0; ks < 2; ++ks) {
        bf16x8 fa[4], fb[4], fal[4], fbl[4];
#pragma unroll
        for (int m = 0; m < 4; ++m) {
            const int r = wr + m * 16 + fr;
            const int o = r * 64 + (((kg | (ks << 2)) ^ (r & 7)) << 3);
            fa[m]  = *(const bf16x8*)&sAH[o];
            fal[m] = *(const bf16x8*)&sAL[o];
        }
#pragma unroll
        for (int n = 0; n < 4; ++n) {
            const int r = wc + n * 16 + fr;
            const int o = r * 64 + (((kg | (ks << 2)) ^ (r & 7)) << 3);
            fb[n]  = *(const bf16x8*)&sBH[o];
            fbl[n] = *(const bf16x8*)&sBL[o];
        }
#pragma unroll
        for (int m = 0; m < 4; ++m)
#pragma unroll
            for (int n = 0; n < 4; ++n) {
                acc[m][n] = __builtin_amdgcn_mfma_f32_16x16x32_bf16(fa[m],  fb[n],  acc[m][n], 0, 0, 0);
                acc[m][n] = __builtin_amdgcn_mfma_f32_16x16x32_bf16(fa[m],  fbl[n], acc[m][n], 0, 0, 0);
                acc[m][n] = __builtin_amdgcn_mfma_f32_16x16x32_bf16(fal[m], fb[n],  acc[m][n], 0, 0, 0);
            }
    }

#pragma unroll
    for (int m = 0; m < 4; ++m) {
        const int r0 = tileM + wr + m * 16 + (kg << 2);
#pragma unroll
        for (int n = 0; n < 4; ++n) {
            const int col = tileN + wc + n * 16 + fr;
#pragma unroll
            for (int i = 0; i < 4; ++i) {
                const float v = acc[m][n][i];
                const long off = zC + (long)(r0 + i) * ldc + col;
                const u16 h = f2bf(v);
                CH[off] = h;
                CL[off] = f2bf(v - bf2f(h));
            }
        }
    }
}

// ---------------------------------------------------------------------------
// PV GEMM, split-K=4, BK=64. 3-pass split. grid (4, 8, NZ).
// ---------------------------------------------------------------------------
__global__ __launch_bounds__(256) void pv_k64(
    const u16* __restrict__ PHp, const u16* __restrict__ PLp,
    const u16* __restrict__ VTH, const u16* __restrict__ VTL,
    float* __restrict__ Op, int Skv, int NZ)
{
    __shared__ u16 smem[24576];
    u16* sAH = smem;
    u16* sAL = smem + 8192;
    u16* sBH = smem + 16384;
    u16* sBL = smem + 20480;

    const int kq = blockIdx.x;
    const int tileM = blockIdx.y * 128;
    const int z = blockIdx.z;
    const int kbase = kq * (Skv >> 2);
    const int nrounds = Skv >> 8;

    const int t = threadIdx.x;
    const int srow = t >> 3;
    const int scol = ((t & 7) ^ (srow & 7)) << 3;
    const u16* pA  = PHp + (long)z * 1024 * Skv + (long)(tileM + srow) * Skv + kbase + scol;
    const u16* pAl = PLp + (long)z * 1024 * Skv + (long)(tileM + srow) * Skv + kbase + scol;
    const u16* pB  = VTH + (long)z * 64 * Skv + (long)srow * Skv + kbase + scol;
    const u16* pBl = VTL + (long)z * 64 * Skv + (long)srow * Skv + kbase + scol;

    const int lane = t & 63, wv = t >> 6;
    const int wr = wv << 5;
    const int fr = lane & 15, kg = lane >> 4;

    f32x4 acc[2][4];
    const f32x4 vzero = {0.f, 0.f, 0.f, 0.f};
#pragma unroll
    for (int m = 0; m < 2; ++m)
#pragma unroll
        for (int n = 0; n < 4; ++n) acc[m][n] = vzero;

    for (int rr = 0; rr < nrounds; ++rr) {
        const long k0 = (long)rr << 6;
#pragma unroll
        for (int c = 0; c < 4; ++c) {
            const long ro = 32L * c * Skv;
            gld16(pA  + k0 + ro, sAH + c * 2048 + t * 8);
            gld16(pAl + k0 + ro, sAL + c * 2048 + t * 8);
        }
#pragma unroll
        for (int c = 0; c < 2; ++c) {
            const long ro = 32L * c * Skv;
            gld16(pB  + k0 + ro, sBH + c * 2048 + t * 8);
            gld16(pBl + k0 + ro, sBL + c * 2048 + t * 8);
        }
        __syncthreads();

#pragma unroll
        for (int ks = 0; ks < 2; ++ks) {
            bf16x8 fa[2], fb[4], fal[2], fbl[4];
#pragma unroll
            for (int m = 0; m < 2; ++m) {
                const int r = wr + m * 16 + fr;
                const int o = r * 64 + (((kg | (ks << 2)) ^ (r & 7)) << 3);
                fa[m]  = *(const bf16x8*)&sAH[o];
                fal[m] = *(const bf16x8*)&sAL[o];
            }
#pragma unroll
            for (int n = 0; n < 4; ++n) {
                const int r = n * 16 + fr;
                const int o = r * 64 + (((kg | (ks << 2)) ^ (r & 7)) << 3);
                fb[n]  = *(const bf16x8*)&sBH[o];
                fbl[n] = *(const bf16x8*)&sBL[o];
            }
#pragma unroll
            for (int m = 0; m < 2; ++m)
#pragma unroll
                for (int n = 0; n < 4; ++n) {
                    acc[m][n] = __builtin_amdgcn_mfma_f32_16x16x32_bf16(fa[m],  fb[n],  acc[m][n], 0, 0, 0);
                    acc[m][n] = __builtin_amdgcn_mfma_f32_16x16x32_bf16(fa[m],  fbl[n], acc[m][n], 0, 0, 0);
                    acc[m][n] = __builtin_amdgcn_mfma_f32_16x16x32_bf16(fal[m], fb[n],  acc[m][n], 0, 0, 0);
                }
        }
        __syncthreads();
    }

    const long base = ((long)kq * NZ + z) * 65536;
#pragma unroll
    for (int m = 0; m < 2; ++m) {
        const int r0 = tileM + wr + m * 16 + (kg << 2);
#pragma unroll
        for (int n = 0; n < 4; ++n) {
            const int col = n * 16 + fr;
#pragma unroll
            for (int i = 0; i < 4; ++i)
                Op[base + (long)(r0 + i) * 64 + col] = acc[m][n][i];
        }
    }
}

// ---------------------------------------------------------------------------
// Sum 4 PV partials, split to aoH/aoL.
// ---------------------------------------------------------------------------
__global__ __launch_bounds__(256) void pv_combine(
    const float* __restrict__ Op, u16* __restrict__ aoH, u16* __restrict__ aoL,
    int nz, int nh)
{
    const long i = ((long)blockIdx.x * 256 + threadIdx.x) * 4;
    const int zz = (int)(i >> 16);
    const int rem = (int)(i & 65535);
    const int r = rem >> 6, c = rem & 63;
    const int b = zz / nh, h = zz % nh;
    const long kqS = (long)nz * 65536;
    float4 v = *(const float4*)(Op + i);
    const float4 v1 = *(const float4*)(Op + kqS + i);
    const float4 v2 = *(const float4*)(Op + 2 * kqS + i);
    const float4 v3 = *(const float4*)(Op + 3 * kqS + i);
    v.x += v1.x + v2.x + v3.x;
    v.y += v1.y + v2.y + v3.y;
    v.z += v1.z + v2.z + v3.z;
    v.w += v1.w + v2.w + v3.w;
    const long dst = (long)b * SDEC * D_ + (long)r * D_ + h * 64 + c;
    u16 h0 = f2bf(v.x), h1 = f2bf(v.y), h2 = f2bf(v.z), h3 = f2bf(v.w);
    uint2 hh;
    hh.x = (unsigned)h0 | ((unsigned)h1 << 16);
    hh.y = (unsigned)h2 | ((unsigned)h3 << 16);
    *(uint2*)(aoH + dst) = hh;
    u16 l0 = f2bf(v.x - bf2f(h0)), l1 = f2bf(v.y - bf2f(h1));
    u16 l2 = f2bf(v.z - bf2f(h2)), l3 = f2bf(v.w - bf2f(h3));
    uint2 ll;
    ll.x = (unsigned)l0 | ((unsigned)l1 << 16);
    ll.y = (unsigned)l2 | ((unsigned)l3 << 16);
    *(uint2*)(aoL + dst) = ll;
}

// ---------------------------------------------------------------------------
// MoE persistent GEMM: 4-slot counted-vmcnt ring, BK=32 (HBM-fed regime).
// ---------------------------------------------------------------------------
template<int EPI>
__global__ __launch_bounds__(256, 2) void moe_gemm2(
    const u16* __restrict__ Ag, int lda,
    const u16* __restrict__ BTbase, int ldb, long btStride,
    float* __restrict__ Cf0, float* __restrict__ Cf1, u16* __restrict__ CH, int ldc,
    const int4* __restrict__ desc, int ndesc, int Kiter)
{
    __shared__ u16 smem[32768];
    const int t = threadIdx.x;
    const int lane = t & 63, wv = t >> 6;
    const int wr = (wv >> 1) << 6, wc = (wv & 1) << 6;
    const int fr = lane & 15, kg = lane >> 4;
    const int nks = Kiter >> 5;

    const int rS = t >> 2;
    const int cS = ((t & 3) ^ ((t >> 3) & 3)) << 3;

    int ldsA[4], ldsB[4];
#pragma unroll
    for (int m = 0; m < 4; ++m) {
        const int ra = wr + m * 16 + fr;
        ldsA[m] = ra * 32 + ((kg ^ ((ra >> 1) & 3)) << 3);
        const int rb = wc + m * 16 + fr;
        ldsB[m] = rb * 32 + ((kg ^ ((rb >> 1) & 3)) << 3);
    }

    for (int p = blockIdx.x; p < ndesc; p += MOEGRID) {
        const int4 d = desc[p];
        if (d.x < 0) continue;
        const int rowbase = d.x, colbase = d.y & 0xFFFF, e = d.y >> 16;
        const int kbase = d.z, s1 = d.w;
        const u16* paS = Ag + (long)(rowbase + rS) * lda + kbase + cS;
        const u16* pbS = BTbase + (long)e * btStride + (long)(colbase + rS) * ldb + kbase + cS;
        const long hA = 64L * lda, hB = 64L * ldb;

        f32x4 acc[4][4];
        const f32x4 vzero = {0.f, 0.f, 0.f, 0.f};
#pragma unroll
        for (int m = 0; m < 4; ++m)
#pragma unroll
            for (int n = 0; n < 4; ++n) acc[m][n] = vzero;

#define STG(ks) { const int s_ = (ks) & 3; const long k0_ = (long)(ks) << 5; \
        u16* b_ = smem + s_ * 8192; \
        gld16(paS + k0_,      b_ + t * 8); \
        gld16(paS + k0_ + hA, b_ + 2048 + t * 8); \
        gld16(pbS + k0_,      b_ + 4096 + t * 8); \
        gld16(pbS + k0_ + hB, b_ + 6144 + t * 8); }

        STG(0); STG(1); STG(2);
        asm volatile("s_waitcnt vmcnt(8)" ::: "memory");
        __builtin_amdgcn_s_barrier();
        __builtin_amdgcn_sched_barrier(0);

        for (int ks = 0; ks < nks; ++ks) {
            if (ks + 3 < nks) STG(ks + 3);
            const u16* sA = smem + (ks & 3) * 8192;
            const u16* sB = sA + 4096;
            bf16x8 fa[4], fb[4];
#pragma unroll
            for (int m = 0; m < 4; ++m) fa[m] = *(const bf16x8*)&sA[ldsA[m]];
#pragma unroll
            for (int n = 0; n < 4; ++n) fb[n] = *(const bf16x8*)&sB[ldsB[n]];
            __builtin_amdgcn_s_setprio(1);
#pragma unroll
            for (int m = 0; m < 4; ++m)
#pragma unroll
                for (int n = 0; n < 4; ++n)
                    acc[m][n] = __builtin_amdgcn_mfma_f32_16x16x32_bf16(fa[m], fb[n], acc[m][n], 0, 0, 0);
            __builtin_amdgcn_s_setprio(0);
            if (ks + 3 < nks)      { asm volatile("s_waitcnt vmcnt(8)" ::: "memory"); }
            else if (ks + 2 < nks) { asm volatile("s_waitcnt vmcnt(4)" ::: "memory"); }
            else                   { asm volatile("s_waitcnt vmcnt(0)" ::: "memory"); }
            __builtin_amdgcn_s_barrier();
            __builtin_amdgcn_sched_barrier(0);
        }
#undef STG

        float* __restrict__ C = (EPI == 0) ? ((kbase == 0) ? Cf0 : Cf1) : nullptr;
#pragma unroll
        for (int m = 0; m < 4; ++m) {
            const int r0 = rowbase + wr + m * 16 + (kg << 2);
#pragma unroll
            for (int n = 0; n < 4; ++n) {
                const int col = colbase + wc + n * 16 + fr;
#pragma unroll
                for (int i = 0; i < 4; ++i) {
                    const int r = r0 + i;
                    if (r >= s1) continue;
                    const float v = acc[m][n][i];
                    const long off = (long)r * ldc + col;
                    if constexpr (EPI == 0) C[off] = v;
                    else                    CH[off] = f2bf(fmaxf(v, 0.f));
                }
            }
        }
    }
}

// ---------------------------------------------------------------------------
__global__ __launch_bounds__(256) void split2k(const float* __restrict__ in,
                                               u16* __restrict__ oh, u16* __restrict__ ol, long n)
{
    long i = ((long)blockIdx.x * 256 + threadIdx.x) * 4;
    if (i >= n) return;
    float4 v = *(const float4*)(in + i);
    u16 h0 = f2bf(v.x), h1 = f2bf(v.y), h2 = f2bf(v.z), h3 = f2bf(v.w);
    uint2 oo;
    oo.x = (unsigned)h0 | ((unsigned)h1 << 16);
    oo.y = (unsigned)h2 | ((unsigned)h3 << 16);
    *(uint2*)(oh + i) = oo;
    if (ol) {
        u16 l0 = f2bf(v.x - bf2f(h0)), l1 = f2bf(v.y - bf2f(h1));
        u16 l2 = f2bf(v.z - bf2f(h2)), l3 = f2bf(v.w - bf2f(h3));
        uint2 ll;
        ll.x = (unsigned)l0 | ((unsigned)l1 << 16);
        ll.y = (unsigned)l2 | ((unsigned)l3 << 16);
        *(uint2*)(ol + i) = ll;
    }
}

// ---------------------------------------------------------------------------
struct Ptr8 { const float* p[8]; };
__global__ __launch_bounds__(256) void transpose_split_w(
    Ptr8 in, u16* __restrict__ oh, u16* __restrict__ ol)
{
    __shared__ float tile[32][33];
    const int z = blockIdx.z;
    const float* ip = in.p[z];
    u16* ohp = oh + (long)z * D_ * D_;
    u16* olp = ol + (long)z * D_ * D_;
    const int c0 = blockIdx.x * 32, r0 = blockIdx.y * 32;
    const int tx = threadIdx.x & 31, ty = threadIdx.x >> 5;
    for (int i = ty; i < 32; i += 8)
        tile[i][tx] = ip[(long)(r0 + i) * D_ + c0 + tx];
    __syncthreads();
    for (int i = ty; i < 32; i += 8) {
        int oc = c0 + i, orr = r0 + tx;
        float v = tile[tx][i];
        u16 h = f2bf(v);
        ohp[(long)oc * D_ + orr] = h;
        olp[(long)oc * D_ + orr] = f2bf(v - bf2f(h));
    }
}

// ---------------------------------------------------------------------------
__global__ __launch_bounds__(256) void transpose_split(
    const float* __restrict__ in, u16* __restrict__ oh, u16* __restrict__ ol,
    int R, int C, int ild, long ibs1, long ibs2, int nb2, int old_, long obs)
{
    __shared__ float tile[32][33];
    const int z = blockIdx.z;
    const float* ip = in + (long)(z / nb2) * ibs1 + (long)(z % nb2) * ibs2;
    u16* ohp = oh + (long)z * obs;
    u16* olp = ol ? ol + (long)z * obs : nullptr;
    const int c0 = blockIdx.x * 32, r0 = blockIdx.y * 32;
    const int tx = threadIdx.x & 31, ty = threadIdx.x >> 5;
    for (int i = ty; i < 32; i += 8) {
        int r = r0 + i, c = c0 + tx;
        tile[i][tx] = (r < R && c < C) ? ip[(long)r * ild + c] : 0.f;
    }
    __syncthreads();
    for (int i = ty; i < 32; i += 8) {
        int oc = c0 + i, orr = r0 + tx;
        if (oc < C && orr < R) {
            float v = tile[tx][i];
            u16 h = f2bf(v);
            ohp[(long)oc * old_ + orr] = h;
            if (olp) olp[(long)oc * old_ + orr] = f2bf(v - bf2f(h));
        }
    }
}

// ---------------------------------------------------------------------------
__global__ __launch_bounds__(256) void transpose_split_hl(
    const u16* __restrict__ inH, const u16* __restrict__ inL,
    u16* __restrict__ oh, u16* __restrict__ ol,
    int R, int C, int ild, long ibs1, long ibs2, int nb2, int old_, long obs)
{
    __shared__ float tile[32][33];
    const int z = blockIdx.z;
    const long base = (long)(z / nb2) * ibs1 + (long)(z % nb2) * ibs2;
    u16* ohp = oh + (long)z * obs;
    u16* olp = ol + (long)z * obs;
    const int c0 = blockIdx.x * 32, r0 = blockIdx.y * 32;
    const int tx = threadIdx.x & 31, ty = threadIdx.x >> 5;
    for (int i = ty; i < 32; i += 8) {
        int r = r0 + i, c = c0 + tx;
        float v = 0.f;
        if (r < R && c < C) {
            const long o = base + (long)r * ild + c;
            v = bf2f(inH[o]) + bf2f(inL[o]);
        }
        tile[i][tx] = v;
    }
    __syncthreads();
    for (int i = ty; i < 32; i += 8) {
        int oc = c0 + i, orr = r0 + tx;
        if (oc < C && orr < R) {
            float v = tile[tx][i];
            u16 h = f2bf(v);
            ohp[(long)oc * old_ + orr] = h;
            olp[(long)oc * old_ + orr] = f2bf(v - bf2f(h));
        }
    }
}

// ---------------------------------------------------------------------------
// In-place softmax over bf16 hi/lo scores.
// ---------------------------------------------------------------------------
__global__ __launch_bounds__(256) void softmax_hl(
    u16* __restrict__ ph, u16* __restrict__ pl, int cols, float scale)
{
    u16* php = ph + (long)blockIdx.x * cols;
    u16* plp = pl + (long)blockIdx.x * cols;
    const int t = threadIdx.x;
    float v[4];
    int vpt;
    if (cols == 1024) {
        vpt = 4;
        uint2 hh = ((const uint2*)php)[t];
        uint2 ll = ((const uint2*)plp)[t];
        v[0] = (bf2f((u16)(hh.x & 0xffff)) + bf2f((u16)(ll.x & 0xffff))) * scale;
        v[1] = (bf2f((u16)(hh.x >> 16))    + bf2f((u16)(ll.x >> 16)))    * scale;
        v[2] = (bf2f((u16)(hh.y & 0xffff)) + bf2f((u16)(ll.y & 0xffff))) * scale;
        v[3] = (bf2f((u16)(hh.y >> 16))    + bf2f((u16)(ll.y >> 16)))    * scale;
    } else {
        vpt = 2;
        unsigned hh = ((const unsigned*)php)[t];
        unsigned ll = ((const unsigned*)plp)[t];
        v[0] = (bf2f((u16)(hh & 0xffff)) + bf2f((u16)(ll & 0xffff))) * scale;
        v[1] = (bf2f((u16)(hh >> 16))    + bf2f((u16)(ll >> 16)))    * scale;
        v[2] = -3.4e38f; v[3] = -3.4e38f;
    }
    float mx = fmaxf(fmaxf(v[0], v[1]), fmaxf(v[2], v[3]));
#pragma unroll
    for (int o = 32; o; o >>= 1) mx = fmaxf(mx, __shfl_xor(mx, o));
    __shared__ float sm[4];
    const int wv = t >> 6, ln = t & 63;
    if (ln == 0) sm[wv] = mx;
    __syncthreads();
    mx = fmaxf(fmaxf(sm[0], sm[1]), fmaxf(sm[2], sm[3]));
    float sum = 0.f;
    for (int i = 0; i < vpt; ++i) { v[i] = expf(v[i] - mx); sum += v[i]; }
#pragma unroll
    for (int o = 32; o; o >>= 1) sum += __shfl_xor(sum, o);
    __shared__ float ss[4];
    if (ln == 0) ss[wv] = sum;
    __syncthreads();
    sum = ss[0] + ss[1] + ss[2] + ss[3];
    const float inv = 1.f / sum;
    if (cols == 1024) {
        float q0 = v[0] * inv, q1 = v[1] * inv, q2 = v[2] * inv, q3 = v[3] * inv;
        u16 h0 = f2bf(q0), h1 = f2bf(q1), h2 = f2bf(q2), h3 = f2bf(q3);
        uint2 hh; hh.x = (unsigned)h0 | ((unsigned)h1 << 16); hh.y = (unsigned)h2 | ((unsigned)h3 << 16);
        ((uint2*)php)[t] = hh;
        u16 l0 = f2bf(q0 - bf2f(h0)), l1 = f2bf(q1 - bf2f(h1));
        u16 l2 = f2bf(q2 - bf2f(h2)), l3 = f2bf(q3 - bf2f(h3));
        uint2 llo; llo.x = (unsigned)l0 | ((unsigned)l1 << 16); llo.y = (unsigned)l2 | ((unsigned)l3 << 16);
        ((uint2*)plp)[t] = llo;
    } else {
        float q0 = v[0] * inv, q1 = v[1] * inv;
        u16 h0 = f2bf(q0), h1 = f2bf(q1);
        ((unsigned*)php)[t] = (unsigned)h0 | ((unsigned)h1 << 16);
        u16 l0 = f2bf(q0 - bf2f(h0)), l1 = f2bf(q1 - bf2f(h1));
        ((unsigned*)plp)[t] = (unsigned)l0 | ((unsigned)l1 << 16);
    }
}

// ---------------------------------------------------------------------------
__global__ __launch_bounds__(256) void add_rmsnorm(
    const float* __restrict__ a, const float* __restrict__ b, const float* __restrict__ g,
    float* __restrict__ xo, u16* __restrict__ xh, u16* __restrict__ xl)
{
    const long row = blockIdx.x;
    const int t = threadIdx.x;
    const float* pa = a + row * D_;
    const float* pb = b + row * D_;
    float v[4]; double ssq = 0.0;
#pragma unroll
    for (int i = 0; i < 4; ++i) {
        int c = t + (i << 8);
        v[i] = pa[c] + pb[c];
        ssq += (double)v[i] * v[i];
    }
#pragma unroll
    for (int o = 32; o; o >>= 1) ssq += __shfl_xor(ssq, o);
    __shared__ double sd[4];
    if ((t & 63) == 0) sd[t >> 6] = ssq;
    __syncthreads();
    ssq = sd[0] + sd[1] + sd[2] + sd[3];
    const float rs = (float)(1.0 / sqrt(ssq * (1.0 / 1024.0) + 1e-6));
#pragma unroll
    for (int i = 0; i < 4; ++i) {
        int c = t + (i << 8);
        float o = v[i] * rs * g[c];
        xo[row * D_ + c] = o;
        if (xh) {
            u16 h = f2bf(o);
            xh[row * D_ + c] = h;
            if (xl) xl[row * D_ + c] = f2bf(o - bf2f(h));
        }
    }
}

// ---------------------------------------------------------------------------
__global__ __launch_bounds__(256) void router_topk(
    const float* __restrict__ x2, const float* __restrict__ Wg,
    float* __restrict__ outw, float* __restrict__ outi,
    int* __restrict__ idx, float* __restrict__ tokw, int* __restrict__ counts, int T)
{
    const int wid = (int)((blockIdx.x * 256 + threadIdx.x) >> 6);
    const int lane = threadIdx.x & 63;
    if (wid >= T) return;
    float acc[NE];
#pragma unroll
    for (int e = 0; e < NE; ++e) acc[e] = 0.f;
    const float* xr = x2 + (long)wid * D_;
    for (int i = 0; i < 16; ++i) {
        float xv = xr[i * 64 + lane];
        const float* wr = Wg + (long)(i * 64 + lane) * NE;
#pragma unroll
        for (int e = 0; e < NE; ++e) acc[e] += xv * wr[e];
    }
#pragma unroll
    for (int e = 0; e < NE; ++e)
#pragma unroll
        for (int o = 32; o; o >>= 1) acc[e] += __shfl_xor(acc[e], o);
    if (lane == 0) {
        float m = acc[0];
#pragma unroll
        for (int e = 1; e < NE; ++e) m = fmaxf(m, acc[e]);
        float p[NE], s = 0.f;
#pragma unroll
        for (int e = 0; e < NE; ++e) { p[e] = expf(acc[e] - m); s += p[e]; }
        const float invs = 1.f / s;
#pragma unroll
        for (int e = 0; e < NE; ++e) p[e] *= invs;
        int e0 = 0;
#pragma unroll
        for (int e = 1; e < NE; ++e) if (p[e] > p[e0]) e0 = e;
        int e1 = (e0 == 0) ? 1 : 0;
#pragma unroll
        for (int e = 0; e < NE; ++e) if (e != e0 && e != e1 && p[e] > p[e1]) e1 = e;
        float w0 = p[e0], w1 = p[e1];
        const float sw = 1.f / (w0 + w1);
        w0 *= sw; w1 *= sw;
        outw[2 * wid] = w0;      outw[2 * wid + 1] = w1;
        outi[2 * wid] = (float)e0; outi[2 * wid + 1] = (float)e1;
        idx[2 * wid] = e0;       idx[2 * wid + 1] = e1;
        tokw[2 * wid] = w0;      tokw[2 * wid + 1] = w1;
        atomicAdd(&counts[e0], 1);
        atomicAdd(&counts[e1], 1);
    }
}

// ---------------------------------------------------------------------------
__global__ void scan_desc(const int* __restrict__ counts, int* __restrict__ cursor,
                          int4* __restrict__ d1, int4* __restrict__ d2)
{
    __shared__ int sseg[NE + 1];
    if (threadIdx.x == 0) {
        int a = 0;
        for (int e = 0; e < NE; ++e) { sseg[e] = a; cursor[e] = a; a += counts[e]; }
        sseg[NE] = a;
    }
    __syncthreads();
    const int e = threadIdx.x;
    if (e < NE) {
        const int s0 = sseg[e], s1 = sseg[e + 1];
        const int nyt = (s1 - s0 + 127) >> 7;
        for (int xt = 0; xt < 32; ++xt)
            for (int yt = 0; yt < nyt; ++yt)
                d1[e + 8 * (xt * nyt + yt)] =
                    make_int4(s0 + yt * 128, (xt * 128) | (e << 16), 0, s1);
        for (int kh = 0; kh < 2; ++kh)
            for (int xt = 0; xt < 8; ++xt)
                for (int yt = 0; yt < nyt; ++yt)
                    d2[e + 8 * ((kh * 8 + xt) * nyt + yt)] =
                        make_int4(s0 + yt * 128, (xt * 128) | (e << 16), kh * 2048, s1);
    }
}

__global__ __launch_bounds__(256) void scatter_slots(
    const int* __restrict__ idx, int* __restrict__ cursor,
    int* __restrict__ row_token, int* __restrict__ slot_of, int T)
{
    const int t = blockIdx.x * 256 + threadIdx.x;
    if (t >= T) return;
#pragma unroll
    for (int k = 0; k < 2; ++k) {
        const int e = idx[2 * t + k];
        const int pos = atomicAdd(&cursor[e], 1);
        row_token[pos] = t;
        slot_of[2 * t + k] = pos;
    }
}

__global__ __launch_bounds__(256) void gather_bf16(
    const float* __restrict__ x2, const int* __restrict__ row_token, u16* __restrict__ Xg)
{
    const int r = blockIdx.x;
    const int t = threadIdx.x;
    const float* src = x2 + (long)row_token[r] * D_ + t * 4;
    float4 v = *(const float4*)src;
    uint2 oo;
    oo.x = (unsigned)f2bf(v.x) | ((unsigned)f2bf(v.y) << 16);
    oo.y = (unsigned)f2bf(v.z) | ((unsigned)f2bf(v.w) << 16);
    *(uint2*)(Xg + (long)r * D_ + t * 4) = oo;
}

// ---------------------------------------------------------------------------
__global__ __launch_bounds__(256) void combine_rmsnorm(
    const float* __restrict__ Y0, const float* __restrict__ Y1,
    const int* __restrict__ slot_of, const float* __restrict__ tokw,
    const float* __restrict__ x2, const float* __restrict__ g, float* __restrict__ out)
{
    const long tr = blockIdx.x;
    const int t = threadIdx.x;
    const int s0 = slot_of[2 * tr], s1 = slot_of[2 * tr + 1];
    const float w0 = tokw[2 * tr], w1 = tokw[2 * tr + 1];
    const float* ya0 = Y0 + (long)s0 * D_;
    const float* yb0 = Y1 + (long)s0 * D_;
    const float* ya1 = Y0 + (long)s1 * D_;
    const float* yb1 = Y1 + (long)s1 * D_;
    const float* xr = x2 + tr * D_;
    float v[4]; double ssq = 0.0;
#pragma unroll
    for (int i = 0; i < 4; ++i) {
        int c = t + (i << 8);
        v[i] = w0 * (ya0[c] + yb0[c]) + w1 * (ya1[c] + yb1[c]) + xr[c];
        ssq += (double)v[i] * v[i];
    }
#pragma unroll
    for (int o = 32; o; o >>= 1) ssq += __shfl_xor(ssq, o);
    __shared__ double sd[4];
    if ((t & 63) == 0) sd[t >> 6] = ssq;
    __syncthreads();
    ssq = sd[0] + sd[1] + sd[2] + sd[3];
    const float rs = (float)(1.0 / sqrt(ssq * (1.0 / 1024.0) + 1e-6));
#pragma unroll
    for (int i = 0; i < 4; ++i) {
        int c = t + (i << 8);
        out[tr * D_ + c] = v[i] * rs * g[c];
    }
}

__global__ void sentinel(float* o) { o[0] = 12345.0f; }

// ---------------------------------------------------------------------------
extern "C" void kernel_launch(void* const* d_in, const int* in_sizes, int n_in,
                              void* d_out, int out_size, void* d_ws, size_t ws_size,
                              hipStream_t stream)
{
    const float* dec = (const float*)d_in[0];
    const float* te  = (const float*)d_in[1];
    const float* g  = (const float*)d_in[10];
    const float* Wg = (const float*)d_in[11];
    const float* W1 = (const float*)d_in[12];
    const float* W2 = (const float*)d_in[13];
    float* outw = (float*)d_out;
    float* outi = outw + 2 * TDEC;
    float* outx = outw + 4 * TDEC;

    char* ws = (char*)d_ws;
    size_t off = 0;
    auto A = [&](size_t bytes) -> char* {
        char* p = ws + off;
        off += (bytes + 255) & ~(size_t)255;
        return p;
    };

    // ---- persistent region ----
    u16* decH = (u16*)A((size_t)TDEC * D_ * 2);
    u16* decL = (u16*)A((size_t)TDEC * D_ * 2);
    u16* teH  = (u16*)A((size_t)TTXT * D_ * 2);
    u16* teL  = (u16*)A((size_t)TTXT * D_ * 2);
    u16* wtHall = (u16*)A((size_t)8 * D_ * D_ * 2);
    u16* wtLall = (u16*)A((size_t)8 * D_ * D_ * 2);
    float* x1f = (float*)A((size_t)TDEC * D_ * 4);
    float* x2f = (float*)A((size_t)TDEC * D_ * 4);
    float* tokw = (float*)A(NSLOT * 4);
    int* idx    = (int*)A(NSLOT * 4);
    int* counts = (int*)A(256);
    int* cursor = (int*)A(256);
    int* row_token = (int*)A(NSLOT * 4);
    int* slot_of   = (int*)A(NSLOT * 4);
    int4* desc1 = (int4*)A((size_t)ND1 * 16);
    int4* desc2 = (int4*)A((size_t)ND2 * 16);
    const size_t Rbase = off;

    // ---- shared region: MoE view ----
    u16* W1T  = (u16*)A((size_t)NE * DFF * D_ * 2);
    u16* W2T  = (u16*)A((size_t)NE * D_ * DFF * 2);
    u16* Xg   = (u16*)A((size_t)(NSLOT + 256) * D_ * 2);
    u16* Hb   = (u16*)A((size_t)(NSLOT + 256) * DFF * 2);
    float* Yseg = (float*)A((size_t)NSLOT * D_ * 4);
    float* Ypart1 = (float*)W1T;
    const size_t moeEnd = off;

    // ---- shared region: attention view (batched preferred, fallback smaller) ----
    auto allocAttn = [&](bool batched, u16*& PH, u16*& PL, u16*& qkvH, u16*& qkvL,
                         u16*& q2H, u16*& q2L, u16*& kv2H, u16*& kv2L,
                         u16*& vTH, u16*& vTL, u16*& aoH, u16*& aoL,
                         u16*& x1H, u16*& x1L, float*& of, float*& Opart) {
        off = Rbase;
        const size_t pcell = batched ? (size_t)BB * NH * SDEC * SDEC * 2
                                     : (size_t)NH * SDEC * SDEC * 2;
        PH = (u16*)A(pcell);
        PL = (u16*)A(pcell);
        qkvH = (u16*)A((size_t)TDEC * 3 * D_ * 2);
        qkvL = (u16*)A((size_t)TDEC * 3 * D_ * 2);
        q2H  = (u16*)A((size_t)TDEC * D_ * 2);
        q2L  = (u16*)A((size_t)TDEC * D_ * 2);
        kv2H = (u16*)A((size_t)TTXT * 2 * D_ * 2);
        kv2L = (u16*)A((size_t)TTXT * 2 * D_ * 2);
        vTH = (u16*)A((size_t)TDEC * D_ * 2);
        vTL = (u16*)A((size_t)TDEC * D_ * 2);
        aoH = (u16*)A((size_t)TDEC * D_ * 2);
        aoL = (u16*)A((size_t)TDEC * D_ * 2);
        x1H = (u16*)A((size_t)TDEC * D_ * 2);
        x1L = (u16*)A((size_t)TDEC * D_ * 2);
        of  = (float*)A((size_t)TDEC * D_ * 4);
        Opart = (float*)A((size_t)4 * (batched ? BB * NH : NH) * SDEC * DHD * 4);
        return off;
    };

    u16 *PH, *PL, *qkvH, *qkvL, *q2H, *q2L, *kv2H, *kv2L, *vTH, *vTL, *aoH, *aoL, *x1H, *x1L;
    float *of, *Opart;
    size_t attnEnd = allocAttn(true, PH, PL, qkvH, qkvL, q2H, q2L, kv2H, kv2L,
                               vTH, vTL, aoH, aoL, x1H, x1L, of, Opart);
    bool batched = ws_size >= (attnEnd > moeEnd ? attnEnd : moeEnd);
    if (!batched) {
        attnEnd = allocAttn(false, PH, PL, qkvH, qkvL, q2H, q2L, kv2H, kv2L,
                            vTH, vTL, aoH, aoL, x1H, x1L, of, Opart);
        if (ws_size < (attnEnd > moeEnd ? attnEnd : moeEnd)) {
            sentinel<<<1, 1, 0, stream>>>(outw);
            return;
        }
    }

    const dim3 blk(256);

    // ---- phase 0: input splits + batched attention weight transposes ----
    split2k<<<dim3((TDEC * D_) / 1024), blk, 0, stream>>>(dec, decH, decL, (long)TDEC * D_);
    split2k<<<dim3((TTXT * D_) / 1024), blk, 0, stream>>>(te, teH, teL, (long)TTXT * D_);
    Ptr8 wp;
    for (int i = 0; i < 8; ++i) wp.p[i] = (const float*)d_in[2 + i];
    transpose_split_w<<<dim3(32, 32, 8), blk, 0, stream>>>(wp, wtHall, wtLall);

    // ---- phase 1: self-attention ----
    proj_k64<1><<<dim3(48, 32), blk, 0, stream>>>(decH, decL, wtHall, wtLall,
        nullptr, qkvH, qkvL, TDEC, 3 * D_, 3 * D_);
    transpose_split_hl<<<dim3(2, 32, BB * NH), blk, 0, stream>>>(qkvH + 2 * D_, qkvL + 2 * D_,
        vTH, vTL, SDEC, DHD, 3 * D_, (long)SDEC * 3 * D_, DHD, NH, SDEC, (long)DHD * SDEC);

    if (batched) {
        scores_k64<<<dim3(8, 8, BB * NH), blk, 0, stream>>>(
            qkvH, qkvL, qkvH + D_, qkvL + D_, PH, PL,
            3 * D_, 3 * D_, SDEC, NH,
            (long)SDEC * 3 * D_, DHD, (long)SDEC * 3 * D_, DHD,
            (long)NH * SDEC * SDEC, (long)SDEC * SDEC);
        softmax_hl<<<dim3(BB * NH * SDEC), blk, 0, stream>>>(PH, PL, SDEC, 0.125f);
        pv_k64<<<dim3(4, 8, BB * NH), blk, 0, stream>>>(PH, PL, vTH, vTL, Opart, SDEC, BB * NH);
        pv_combine<<<dim3(BB * NH * 64), blk, 0, stream>>>(Opart, aoH, aoL, BB * NH, NH);
    } else {
        for (int b = 0; b < BB; ++b) {
            const long qo3 = (long)b * SDEC * 3 * D_;
            const long qo  = (long)b * SDEC * D_;
            scores_k64<<<dim3(8, 8, NH), blk, 0, stream>>>(
                qkvH + qo3, qkvL + qo3, qkvH + qo3 + D_, qkvL + qo3 + D_,
                PH, PL, 3 * D_, 3 * D_, SDEC, NH,
                0, DHD, 0, DHD, 0, (long)SDEC * SDEC);
            softmax_hl<<<dim3(NH * SDEC), blk, 0, stream>>>(PH, PL, SDEC, 0.125f);
            pv_k64<<<dim3(4, 8, NH), blk, 0, stream>>>(PH, PL,
                vTH + (long)b * NH * DHD * SDEC, vTL + (long)b * NH * DHD * SDEC,
                Opart, SDEC, NH);
            pv_combine<<<dim3(NH * 64), blk, 0, stream>>>(Opart, aoH + qo, aoL + qo, NH, NH);
        }
    }
    proj_k64<0><<<dim3(16, 32), blk, 0, stream>>>(aoH, aoL,
        wtHall + (size_t)3 * D_ * D_, wtLall + (size_t)3 * D_ * D_,
        of, nullptr, nullptr, TDEC, D_, D_);
    add_rmsnorm<<<dim3(TDEC), blk, 0, stream>>>(of, dec, g, x1f, x1H, x1L);

    // ---- phase 2: cross-attention ----
    proj_k64<1><<<dim3(16, 32), blk, 0, stream>>>(x1H, x1L,
        wtHall + (size_t)4 * D_ * D_, wtLall + (size_t)4 * D_ * D_,
        nullptr, q2H, q2L, TDEC, D_, D_);
    proj_k64<1><<<dim3(32, 16), blk, 0, stream>>>(teH, teL,
        wtHall + (size_t)5 * D_ * D_, wtLall + (size_t)5 * D_ * D_,
        nullptr, kv2H, kv2L, TTXT, 2 * D_, 2 * D_);
    transpose_split_hl<<<dim3(2, 16, BB * NH), blk, 0, stream>>>(kv2H + D_, kv2L + D_,
        vTH, vTL, STXT, DHD, 2 * D_, (long)STXT * 2 * D_, DHD, NH, STXT, (long)DHD * STXT);

    if (batched) {
        scores_k64<<<dim3(4, 8, BB * NH), blk, 0, stream>>>(
            q2H, q2L, kv2H, kv2L, PH, PL,
            D_, 2 * D_, STXT, NH,
            (long)SDEC * D_, DHD, (long)STXT * 2 * D_, DHD,
            (long)NH * SDEC * STXT, (long)SDEC * STXT);
        softmax_hl<<<dim3(BB * NH * SDEC), blk, 0, stream>>>(PH, PL, STXT, 0.125f);
        pv_k64<<<dim3(4, 8, BB * NH), blk, 0, stream>>>(PH, PL, vTH, vTL, Opart, STXT, BB * NH);
        pv_combine<<<dim3(BB * NH * 64), blk, 0, stream>>>(Opart, aoH, aoL, BB * NH, NH);
    } else {
        for (int b = 0; b < BB; ++b) {
            const long qo  = (long)b * SDEC * D_;
            const long ko2 = (long)b * STXT * 2 * D_;
            scores_k64<<<dim3(4, 8, NH), blk, 0, stream>>>(
                q2H + qo, q2L + qo, kv2H + ko2, kv2L + ko2,
                PH, PL, D_, 2 * D_, STXT, NH,
                0, DHD, 0, DHD, 0, (long)SDEC * STXT);
            softmax_hl<<<dim3(NH * SDEC), blk, 0, stream>>>(PH, PL, STXT, 0.125f);
            pv_k64<<<dim3(4, 8, NH), blk, 0, stream>>>(PH, PL,
                vTH + (long)b * NH * DHD * STXT, vTL + (long)b * NH * DHD * STXT,
                Opart, STXT, NH);
            pv_combine<<<dim3(NH * 64), blk, 0, stream>>>(Opart, aoH + qo, aoL + qo, NH, NH);
        }
    }
    proj_k64<0><<<dim3(16, 32), blk, 0, stream>>>(aoH, aoL,
        wtHall + (size_t)7 * D_ * D_, wtLall + (size_t)7 * D_ * D_,
        of, nullptr, nullptr, TDEC, D_, D_);
    add_rmsnorm<<<dim3(TDEC), blk, 0, stream>>>(of, x1f, g, x2f, nullptr, nullptr);

    // ---- phase 3: router + expert bucketing + work lists ----
    hipMemsetAsync(counts, 0, 32, stream);
    hipMemsetAsync(desc1, 0xFF, (size_t)ND1 * 16, stream);
    hipMemsetAsync(desc2, 0xFF, (size_t)ND2 * 16, stream);
    router_topk<<<dim3(TDEC / 4), blk, 0, stream>>>(x2f, Wg, outw, outi, idx, tokw, counts, TDEC);
    scan_desc<<<1, 64, 0, stream>>>(counts, cursor, desc1, desc2);
    scatter_slots<<<dim3(TDEC / 256), blk, 0, stream>>>(idx, cursor, row_token, slot_of, TDEC);
    gather_bf16<<<dim3(NSLOT), blk, 0, stream>>>(x2f, row_token, Xg);

    // ---- phase 4: MoE FFN (persistent 128x128, 4-slot ring) ----
    transpose_split<<<dim3(DFF / 32, D_ / 32, NE), blk, 0, stream>>>(W1, W1T, nullptr,
        D_, DFF, DFF, (long)D_ * DFF, 0, 1, D_, (long)DFF * D_);
    transpose_split<<<dim3(D_ / 32, DFF / 32, NE), blk, 0, stream>>>(W2, W2T, nullptr,
        DFF, D_, D_, (long)D_ * DFF, 0, 1, DFF, (long)D_ * DFF);
    moe_gemm2<2><<<dim3(MOEGRID), blk, 0, stream>>>(Xg, D_, W1T, D_, (long)DFF * D_,
        nullptr, nullptr, Hb, DFF, desc1, ND1, 1024);
    moe_gemm2<0><<<dim3(MOEGRID), blk, 0, stream>>>(Hb, DFF, W2T, DFF, (long)D_ * DFF,
        Yseg, Ypart1, nullptr, D_, desc2, ND2, 2048);
    combine_rmsnorm<<<dim3(TDEC), blk, 0, stream>>>(Yseg, Ypart1, slot_of, tokw, x2f, g, outx);

    (void)in_sizes; (void)n_in; (void)out_size;
}